// Round 1
// baseline (2802.133 us; speedup 1.0000x reference)
//
#include <hip/hip_runtime.h>
#include <math.h>

// Problem constants (match reference setup_inputs)
constexpr int NN   = 50000;   // nodes
constexpr int NE   = 800000;  // edges
constexpr int NEP  = 200000;  // pred edges

// ---------------- degree / normalization ----------------
__global__ void k_init_deg(float* __restrict__ deg, int n) {
    int i = blockIdx.x * blockDim.x + threadIdx.x;
    if (i < n) deg[i] = 1.0f;   // self-loop
}

__global__ void k_count_deg(const int* __restrict__ dst, float* __restrict__ deg, int e) {
    int i = blockIdx.x * blockDim.x + threadIdx.x;
    if (i < e) atomicAdd(&deg[dst[i]], 1.0f);
}

__global__ void k_rsqrt(float* __restrict__ deg, int n) {
    int i = blockIdx.x * blockDim.x + threadIdx.x;
    if (i < n) deg[i] = rsqrtf(deg[i]);
}

// ---------------- dense GEMM h = (relu?)x @ W ----------------
// One thread per output element. W read through cache (<=64KB, L2-hot).
template<int DIN, int DOUT, bool RELU_IN>
__global__ void k_gemm(const float* __restrict__ x, const float* __restrict__ W,
                       float* __restrict__ h, int n) {
    int tid = blockIdx.x * blockDim.x + threadIdx.x;
    if (tid >= n * DOUT) return;
    int row = tid / DOUT;
    int col = tid - row * DOUT;
    const float* xr = x + (size_t)row * DIN;
    float acc = 0.f;
#pragma unroll 8
    for (int k = 0; k < DIN; ++k) {
        float xv = xr[k];
        if (RELU_IN) xv = fmaxf(xv, 0.f);
        acc = fmaf(xv, W[k * DOUT + col], acc);
    }
    h[tid] = acc;
}

// ---------------- self term + bias: out = h*dis^2 + b ----------------
template<int DOUT>
__global__ void k_self(const float* __restrict__ h, const float* __restrict__ dis,
                       const float* __restrict__ b, float* __restrict__ out, int n) {
    int tid = blockIdx.x * blockDim.x + threadIdx.x;
    if (tid >= n * DOUT) return;
    int row = tid / DOUT;
    int col = tid - row * DOUT;
    float d = dis[row];
    out[tid] = fmaf(h[tid], d * d, b[col]);
}

// ---------------- edge aggregation: out[dst] += h[src]*dis[src]*dis[dst] ----------------
// One thread per (edge, 4-channel group): float4 gather + 4 atomicAdds.
template<int DOUT>
__global__ void k_scatter(const float* __restrict__ h, const float* __restrict__ dis,
                          const int* __restrict__ src, const int* __restrict__ dst,
                          float* __restrict__ out, int e) {
    constexpr int DV = DOUT / 4;
    int tid = blockIdx.x * blockDim.x + threadIdx.x;
    if (tid >= e * DV) return;
    int ei = tid / DV;
    int c4 = tid - ei * DV;
    int s = src[ei], d = dst[ei];
    float w = dis[s] * dis[d];
    float4 hv = *(const float4*)(h + (size_t)s * DOUT + c4 * 4);
    float* op = out + (size_t)d * DOUT + c4 * 4;
    atomicAdd(op + 0, hv.x * w);
    atomicAdd(op + 1, hv.y * w);
    atomicAdd(op + 2, hv.z * w);
    atomicAdd(op + 3, hv.w * w);
}

// ---------------- MLP head: relu(in)@lw0+lb0 -> relu -> @lw1+lb1 -> relu -> @lw2+lb2 -> sigmoid ----------------
__global__ void k_mlp(const float* __restrict__ xin,
                      const float* __restrict__ lw0, const float* __restrict__ lb0,
                      const float* __restrict__ lw1, const float* __restrict__ lb1,
                      const float* __restrict__ lw2, const float* __restrict__ lb2,
                      float* __restrict__ s, int n) {
    int i = blockIdx.x * blockDim.x + threadIdx.x;
    if (i >= n) return;
    float v[32];
    const float4* xp = (const float4*)(xin + (size_t)i * 32);
#pragma unroll
    for (int q = 0; q < 8; ++q) {
        float4 t = xp[q];
        v[4 * q + 0] = fmaxf(t.x, 0.f);
        v[4 * q + 1] = fmaxf(t.y, 0.f);
        v[4 * q + 2] = fmaxf(t.z, 0.f);
        v[4 * q + 3] = fmaxf(t.w, 0.f);
    }
    float a[16];
#pragma unroll
    for (int j = 0; j < 16; ++j) {
        float acc = lb0[j];
#pragma unroll
        for (int k = 0; k < 32; ++k) acc = fmaf(v[k], lw0[k * 16 + j], acc);
        a[j] = fmaxf(acc, 0.f);
    }
    float b8[8];
#pragma unroll
    for (int j = 0; j < 8; ++j) {
        float acc = lb1[j];
#pragma unroll
        for (int k = 0; k < 16; ++k) acc = fmaf(a[k], lw1[k * 8 + j], acc);
        b8[j] = fmaxf(acc, 0.f);
    }
    float z = lb2[0];
#pragma unroll
    for (int k = 0; k < 8; ++k) z = fmaf(b8[k], lw2[k], z);
    s[i] = 1.0f / (1.0f + expf(-z));
}

// ---------------- link prediction ----------------
__global__ void k_pred(const float* __restrict__ s, const int* __restrict__ pe,
                       float* __restrict__ out, int ep) {
    int i = blockIdx.x * blockDim.x + threadIdx.x;
    if (i < ep) out[i] = s[pe[2 * i]] * s[pe[2 * i + 1]];
}

static inline int cdiv(long long a, int b) { return (int)((a + b - 1) / b); }

extern "C" void kernel_launch(void* const* d_in, const int* in_sizes, int n_in,
                              void* d_out, int out_size, void* d_ws, size_t ws_size,
                              hipStream_t stream) {
    const float* x   = (const float*)d_in[0];
    const int*   ei  = (const int*)d_in[1];
    const int*   pe  = (const int*)d_in[2];
    const float* cw0 = (const float*)d_in[3];
    const float* cb0 = (const float*)d_in[4];
    const float* cw1 = (const float*)d_in[5];
    const float* cb1 = (const float*)d_in[6];
    const float* cw2 = (const float*)d_in[7];
    const float* cb2 = (const float*)d_in[8];
    const float* lw0 = (const float*)d_in[9];
    const float* lb0 = (const float*)d_in[10];
    const float* lw1 = (const float*)d_in[11];
    const float* lb1 = (const float*)d_in[12];
    const float* lw2 = (const float*)d_in[13];
    const float* lb2 = (const float*)d_in[14];

    const int* src = ei;        // edge_index[0]
    const int* dst = ei + NE;   // edge_index[1]

    float* ws  = (float*)d_ws;
    float* dis = ws;                       // N
    float* A   = ws + NN;                  // N x 128 (h buffer)
    float* B   = A + (size_t)NN * 128;     // N x 128 (in/out ping)
    float* sv  = B + (size_t)NN * 128;     // N (node scores)

    const int T = 256;

    // normalization coefficients
    k_init_deg<<<cdiv(NN, T), T, 0, stream>>>(dis, NN);
    k_count_deg<<<cdiv(NE, T), T, 0, stream>>>(dst, dis, NE);
    k_rsqrt<<<cdiv(NN, T), T, 0, stream>>>(dis, NN);

    // conv0: 128 -> 128 (input raw x)
    k_gemm<128, 128, false><<<cdiv((long long)NN * 128, T), T, 0, stream>>>(x, cw0, A, NN);
    k_self<128><<<cdiv((long long)NN * 128, T), T, 0, stream>>>(A, dis, cb0, B, NN);
    k_scatter<128><<<cdiv((long long)NE * 32, T), T, 0, stream>>>(A, dis, src, dst, B, NE);

    // conv1: 128 -> 64 (relu on input)
    k_gemm<128, 64, true><<<cdiv((long long)NN * 64, T), T, 0, stream>>>(B, cw1, A, NN);
    k_self<64><<<cdiv((long long)NN * 64, T), T, 0, stream>>>(A, dis, cb1, B, NN);
    k_scatter<64><<<cdiv((long long)NE * 16, T), T, 0, stream>>>(A, dis, src, dst, B, NE);

    // conv2: 64 -> 32 (relu on input)
    k_gemm<64, 32, true><<<cdiv((long long)NN * 32, T), T, 0, stream>>>(B, cw2, A, NN);
    k_self<32><<<cdiv((long long)NN * 32, T), T, 0, stream>>>(A, dis, cb2, B, NN);
    k_scatter<32><<<cdiv((long long)NE * 8, T), T, 0, stream>>>(A, dis, src, dst, B, NE);

    // MLP head (relu on input) -> node scores
    k_mlp<<<cdiv(NN, T), T, 0, stream>>>(B, lw0, lb0, lw1, lb1, lw2, lb2, sv, NN);

    // link prediction
    k_pred<<<cdiv(NEP, T), T, 0, stream>>>(sv, pe, (float*)d_out, NEP);
}

// Round 2
// 666.510 us; speedup vs baseline: 4.2042x; 4.2042x over previous
//
#include <hip/hip_runtime.h>
#include <math.h>

constexpr int NN  = 50000;   // nodes
constexpr int NE  = 800000;  // edges
constexpr int NEP = 200000;  // pred edges

static inline int cdiv(long long a, int b) { return (int)((a + b - 1) / b); }

// ---------------- CSR build ----------------
__global__ void k_zero_i(int* __restrict__ p, int n) {
    int i = blockIdx.x * blockDim.x + threadIdx.x;
    if (i < n) p[i] = 0;
}

__global__ void k_count(const int* __restrict__ dst, int* __restrict__ cnt, int e) {
    int i = blockIdx.x * blockDim.x + threadIdx.x;
    if (i < e) atomicAdd(&cnt[dst[i]], 1);
}

// per-256-block exclusive scan; writes local exclusive to off, block total to bsum
__global__ void k_scan_local(const int* __restrict__ cnt, int* __restrict__ off,
                             int* __restrict__ bsum, int n) {
    __shared__ int sh[256];
    int i = blockIdx.x * 256 + threadIdx.x;
    int v = (i < n) ? cnt[i] : 0;
    sh[threadIdx.x] = v;
    __syncthreads();
    for (int d = 1; d < 256; d <<= 1) {
        int t = (threadIdx.x >= d) ? sh[threadIdx.x - d] : 0;
        __syncthreads();
        sh[threadIdx.x] += t;
        __syncthreads();
    }
    if (i < n) off[i] = sh[threadIdx.x] - v;  // exclusive
    if (threadIdx.x == 255) bsum[blockIdx.x] = sh[255];
}

// single-block exclusive scan of block sums (nb <= 256)
__global__ void k_scan_bsum(int* __restrict__ bsum, int nb) {
    __shared__ int sh[256];
    int v = (threadIdx.x < nb) ? bsum[threadIdx.x] : 0;
    sh[threadIdx.x] = v;
    __syncthreads();
    for (int d = 1; d < 256; d <<= 1) {
        int t = (threadIdx.x >= d) ? sh[threadIdx.x - d] : 0;
        __syncthreads();
        sh[threadIdx.x] += t;
        __syncthreads();
    }
    if (threadIdx.x < nb) bsum[threadIdx.x] = sh[threadIdx.x] - v;  // exclusive
}

__global__ void k_finalize_off(int* __restrict__ off, const int* __restrict__ bsum,
                               int* __restrict__ cur, int n, int e) {
    int i = blockIdx.x * blockDim.x + threadIdx.x;
    if (i < n) {
        int o = off[i] + bsum[i >> 8];
        off[i] = o;
        cur[i] = o;
    }
    if (i == 0) off[n] = e;
}

__global__ void k_fill(const int* __restrict__ src, const int* __restrict__ dst,
                       int* __restrict__ cur, int* __restrict__ csr, int e) {
    int i = blockIdx.x * blockDim.x + threadIdx.x;
    if (i < e) {
        int d = dst[i];
        int p = atomicAdd(&cur[d], 1);
        csr[p] = src[i];
    }
}

__global__ void k_dis_from_cnt(const int* __restrict__ cnt, float* __restrict__ dis, int n) {
    int i = blockIdx.x * blockDim.x + threadIdx.x;
    if (i < n) dis[i] = rsqrtf((float)cnt[i] + 1.0f);
}

// ---------------- dense GEMM h = (relu?)x @ W ----------------
template<int DIN, int DOUT, bool RELU_IN>
__global__ void k_gemm(const float* __restrict__ x, const float* __restrict__ W,
                       float* __restrict__ h, int n) {
    int tid = blockIdx.x * blockDim.x + threadIdx.x;
    if (tid >= n * DOUT) return;
    int row = tid / DOUT;
    int col = tid - row * DOUT;
    const float* xr = x + (size_t)row * DIN;
    float acc = 0.f;
#pragma unroll 8
    for (int k = 0; k < DIN; ++k) {
        float xv = xr[k];
        if (RELU_IN) xv = fmaxf(xv, 0.f);
        acc = fmaf(xv, W[k * DOUT + col], acc);
    }
    h[tid] = acc;
}

// ---------------- CSR gather aggregation ----------------
// out[d] = h[d]*dis[d]^2 + b + sum_{s in N(d)} h[s]*dis[s]*dis[d]
template<int DOUT>
__global__ void k_aggregate(const float* __restrict__ h, const float* __restrict__ dis,
                            const float* __restrict__ b, const int* __restrict__ off,
                            const int* __restrict__ csr, float* __restrict__ out, int n) {
    constexpr int TPN = (DOUT >= 64) ? 64 : DOUT;  // threads per node
    constexpr int CPT = DOUT / TPN;                // channels per thread
    const int npb = 256 / TPN;
    int local = threadIdx.x / TPN;
    int lane  = threadIdx.x % TPN;
    int node  = blockIdx.x * npb + local;
    if (node >= n) return;
    float dd = dis[node];
    float acc[CPT];
#pragma unroll
    for (int c = 0; c < CPT; ++c) {
        int ch = lane + c * TPN;
        acc[c] = fmaf(h[(size_t)node * DOUT + ch], dd * dd, b[ch]);
    }
    int e0 = off[node], e1 = off[node + 1];
    int e = e0;
    // 2-neighbor unroll for load ILP
    for (; e + 1 < e1; e += 2) {
        int s0 = csr[e], s1 = csr[e + 1];
        float w0 = dis[s0] * dd, w1 = dis[s1] * dd;
        const float* h0 = h + (size_t)s0 * DOUT + lane;
        const float* h1 = h + (size_t)s1 * DOUT + lane;
#pragma unroll
        for (int c = 0; c < CPT; ++c) {
            float v0 = h0[c * TPN];
            float v1 = h1[c * TPN];
            acc[c] = fmaf(v0, w0, acc[c]);
            acc[c] = fmaf(v1, w1, acc[c]);
        }
    }
    if (e < e1) {
        int s0 = csr[e];
        float w0 = dis[s0] * dd;
        const float* h0 = h + (size_t)s0 * DOUT + lane;
#pragma unroll
        for (int c = 0; c < CPT; ++c) acc[c] = fmaf(h0[c * TPN], w0, acc[c]);
    }
#pragma unroll
    for (int c = 0; c < CPT; ++c) out[(size_t)node * DOUT + lane + c * TPN] = acc[c];
}

// ---------------- MLP head ----------------
__global__ void k_mlp(const float* __restrict__ xin,
                      const float* __restrict__ lw0, const float* __restrict__ lb0,
                      const float* __restrict__ lw1, const float* __restrict__ lb1,
                      const float* __restrict__ lw2, const float* __restrict__ lb2,
                      float* __restrict__ s, int n) {
    int i = blockIdx.x * blockDim.x + threadIdx.x;
    if (i >= n) return;
    float v[32];
    const float4* xp = (const float4*)(xin + (size_t)i * 32);
#pragma unroll
    for (int q = 0; q < 8; ++q) {
        float4 t = xp[q];
        v[4 * q + 0] = fmaxf(t.x, 0.f);
        v[4 * q + 1] = fmaxf(t.y, 0.f);
        v[4 * q + 2] = fmaxf(t.z, 0.f);
        v[4 * q + 3] = fmaxf(t.w, 0.f);
    }
    float a[16];
#pragma unroll
    for (int j = 0; j < 16; ++j) {
        float acc = lb0[j];
#pragma unroll
        for (int k = 0; k < 32; ++k) acc = fmaf(v[k], lw0[k * 16 + j], acc);
        a[j] = fmaxf(acc, 0.f);
    }
    float b8[8];
#pragma unroll
    for (int j = 0; j < 8; ++j) {
        float acc = lb1[j];
#pragma unroll
        for (int k = 0; k < 16; ++k) acc = fmaf(a[k], lw1[k * 8 + j], acc);
        b8[j] = fmaxf(acc, 0.f);
    }
    float z = lb2[0];
#pragma unroll
    for (int k = 0; k < 8; ++k) z = fmaf(b8[k], lw2[k], z);
    s[i] = 1.0f / (1.0f + expf(-z));
}

__global__ void k_pred(const float* __restrict__ s, const int* __restrict__ pe,
                       float* __restrict__ out, int ep) {
    int i = blockIdx.x * blockDim.x + threadIdx.x;
    if (i < ep) out[i] = s[pe[2 * i]] * s[pe[2 * i + 1]];
}

extern "C" void kernel_launch(void* const* d_in, const int* in_sizes, int n_in,
                              void* d_out, int out_size, void* d_ws, size_t ws_size,
                              hipStream_t stream) {
    const float* x   = (const float*)d_in[0];
    const int*   ei  = (const int*)d_in[1];
    const int*   pe  = (const int*)d_in[2];
    const float* cw0 = (const float*)d_in[3];
    const float* cb0 = (const float*)d_in[4];
    const float* cw1 = (const float*)d_in[5];
    const float* cb1 = (const float*)d_in[6];
    const float* cw2 = (const float*)d_in[7];
    const float* cb2 = (const float*)d_in[8];
    const float* lw0 = (const float*)d_in[9];
    const float* lb0 = (const float*)d_in[10];
    const float* lw1 = (const float*)d_in[11];
    const float* lb1 = (const float*)d_in[12];
    const float* lw2 = (const float*)d_in[13];
    const float* lb2 = (const float*)d_in[14];

    const int* src = ei;        // edge_index[0]
    const int* dst = ei + NE;   // edge_index[1]

    // workspace layout
    char* w = (char*)d_ws;
    float* dis = (float*)w;                 w += sizeof(float) * NN;
    float* A   = (float*)w;                 w += sizeof(float) * (size_t)NN * 128;
    float* B   = (float*)w;                 w += sizeof(float) * (size_t)NN * 128;
    float* sv  = (float*)w;                 w += sizeof(float) * NN;
    int*   cnt = (int*)w;                   w += sizeof(int) * NN;
    int*   off = (int*)w;                   w += sizeof(int) * (NN + 1);
    int*   cur = (int*)w;                   w += sizeof(int) * NN;
    int*   csr = (int*)w;                   w += sizeof(int) * NE;
    int*   bsum = (int*)w;                  w += sizeof(int) * 256;

    const int T = 256;
    const int NB = cdiv(NN, 256);  // 196 scan blocks

    // --- CSR build + normalization ---
    k_zero_i<<<cdiv(NN, T), T, 0, stream>>>(cnt, NN);
    k_count<<<cdiv(NE, T), T, 0, stream>>>(dst, cnt, NE);
    k_dis_from_cnt<<<cdiv(NN, T), T, 0, stream>>>(cnt, dis, NN);
    k_scan_local<<<NB, 256, 0, stream>>>(cnt, off, bsum, NN);
    k_scan_bsum<<<1, 256, 0, stream>>>(bsum, NB);
    k_finalize_off<<<cdiv(NN, T), T, 0, stream>>>(off, bsum, cur, NN, NE);
    k_fill<<<cdiv(NE, T), T, 0, stream>>>(src, dst, cur, csr, NE);

    // --- conv0: 128 -> 128 ---
    k_gemm<128, 128, false><<<cdiv((long long)NN * 128, T), T, 0, stream>>>(x, cw0, A, NN);
    k_aggregate<128><<<cdiv(NN, 256 / 64), 256, 0, stream>>>(A, dis, cb0, off, csr, B, NN);

    // --- conv1: 128 -> 64 (relu on input) ---
    k_gemm<128, 64, true><<<cdiv((long long)NN * 64, T), T, 0, stream>>>(B, cw1, A, NN);
    k_aggregate<64><<<cdiv(NN, 256 / 64), 256, 0, stream>>>(A, dis, cb1, off, csr, B, NN);

    // --- conv2: 64 -> 32 (relu on input) ---
    k_gemm<64, 32, true><<<cdiv((long long)NN * 32, T), T, 0, stream>>>(B, cw2, A, NN);
    k_aggregate<32><<<cdiv(NN, 256 / 32), 256, 0, stream>>>(A, dis, cb2, off, csr, B, NN);

    // --- MLP head + link prediction ---
    k_mlp<<<cdiv(NN, T), T, 0, stream>>>(B, lw0, lb0, lw1, lb1, lw2, lb2, sv, NN);
    k_pred<<<cdiv(NEP, T), T, 0, stream>>>(sv, pe, (float*)d_out, NEP);
}

// Round 3
// 409.161 us; speedup vs baseline: 6.8485x; 1.6290x over previous
//
#include <hip/hip_runtime.h>
#include <math.h>

constexpr int NN  = 50000;   // nodes
constexpr int NE  = 800000;  // edges
constexpr int NEP = 200000;  // pred edges

static inline int cdiv(long long a, int b) { return (int)((a + b - 1) / b); }

// ---------------- CSR build ----------------
__global__ void k_zero_i(int* __restrict__ p, int n) {
    int i = blockIdx.x * blockDim.x + threadIdx.x;
    if (i < n) p[i] = 0;
}

__global__ void k_count(const int* __restrict__ dst, int* __restrict__ cnt, int e) {
    int i = blockIdx.x * blockDim.x + threadIdx.x;
    if (i < e) atomicAdd(&cnt[dst[i]], 1);
}

__global__ void k_scan_local(const int* __restrict__ cnt, int* __restrict__ off,
                             int* __restrict__ bsum, int n) {
    __shared__ int sh[256];
    int i = blockIdx.x * 256 + threadIdx.x;
    int v = (i < n) ? cnt[i] : 0;
    sh[threadIdx.x] = v;
    __syncthreads();
    for (int d = 1; d < 256; d <<= 1) {
        int t = (threadIdx.x >= d) ? sh[threadIdx.x - d] : 0;
        __syncthreads();
        sh[threadIdx.x] += t;
        __syncthreads();
    }
    if (i < n) off[i] = sh[threadIdx.x] - v;  // exclusive
    if (threadIdx.x == 255) bsum[blockIdx.x] = sh[255];
}

__global__ void k_scan_bsum(int* __restrict__ bsum, int nb) {
    __shared__ int sh[256];
    int v = (threadIdx.x < nb) ? bsum[threadIdx.x] : 0;
    sh[threadIdx.x] = v;
    __syncthreads();
    for (int d = 1; d < 256; d <<= 1) {
        int t = (threadIdx.x >= d) ? sh[threadIdx.x - d] : 0;
        __syncthreads();
        sh[threadIdx.x] += t;
        __syncthreads();
    }
    if (threadIdx.x < nb) bsum[threadIdx.x] = sh[threadIdx.x] - v;  // exclusive
}

__global__ void k_finalize_off(int* __restrict__ off, const int* __restrict__ bsum,
                               int* __restrict__ cur, int n, int e) {
    int i = blockIdx.x * blockDim.x + threadIdx.x;
    if (i < n) {
        int o = off[i] + bsum[i >> 8];
        off[i] = o;
        cur[i] = o;
    }
    if (i == 0) off[n] = e;
}

__global__ void k_fill(const int* __restrict__ src, const int* __restrict__ dst,
                       int* __restrict__ cur, int* __restrict__ csr, int e) {
    int i = blockIdx.x * blockDim.x + threadIdx.x;
    if (i < e) {
        int d = dst[i];
        int p = atomicAdd(&cur[d], 1);
        csr[p] = src[i];
    }
}

__global__ void k_dis_from_cnt(const int* __restrict__ cnt, float* __restrict__ dis, int n) {
    int i = blockIdx.x * blockDim.x + threadIdx.x;
    if (i < n) dis[i] = rsqrtf((float)cnt[i] + 1.0f);
}

// ---------------- register-tiled GEMM: h = (relu?)x @ W ----------------
// 256 threads; block computes ROWS x DOUT. Thread: 4 rows x COLS cols.
// x tile staged in LDS with stride K+1 (conflict-free b32 reads).
// W streamed from global (small, L1/L2-hot, broadcast-coalesced).
template<int K, int DOUT, int COLS, bool RELU_IN>
__global__ __launch_bounds__(256) void k_gemm_tiled(const float* __restrict__ x,
        const float* __restrict__ W, float* __restrict__ h, int n) {
    constexpr int CG   = DOUT / COLS;  // column groups
    constexpr int RG   = 256 / CG;     // row groups
    constexpr int ROWS = 4 * RG;       // rows per block
    constexpr int XS   = K + 1;        // padded LDS stride
    constexpr int CQ   = COLS / 4;
    __shared__ float sX[ROWS * XS];

    const int tid  = threadIdx.x;
    const int row0 = blockIdx.x * ROWS;

    // stage x tile (8 float4 loads per thread), relu fused
    constexpr int NLD = ROWS * K / 4 / 256;
#pragma unroll
    for (int i = 0; i < NLD; ++i) {
        int idx = tid + i * 256;
        int r   = idx / (K / 4);
        int kq  = (idx - r * (K / 4)) * 4;
        float4 v = make_float4(0.f, 0.f, 0.f, 0.f);
        if (row0 + r < n) v = *(const float4*)(x + (size_t)(row0 + r) * K + kq);
        if (RELU_IN) {
            v.x = fmaxf(v.x, 0.f); v.y = fmaxf(v.y, 0.f);
            v.z = fmaxf(v.z, 0.f); v.w = fmaxf(v.w, 0.f);
        }
        float* p = sX + r * XS + kq;
        p[0] = v.x; p[1] = v.y; p[2] = v.z; p[3] = v.w;
    }
    __syncthreads();

    const int cg = tid % CG;
    const int rg = tid / CG;
    const float* xp = sX + rg * 4 * XS;
    const float* wp = W + cg * COLS;

    float acc[4][COLS];
#pragma unroll
    for (int i = 0; i < 4; ++i)
#pragma unroll
        for (int c = 0; c < COLS; ++c) acc[i][c] = 0.f;

#pragma unroll 4
    for (int k = 0; k < K; ++k) {
        float xv[4];
        xv[0] = xp[k];
        xv[1] = xp[XS + k];
        xv[2] = xp[2 * XS + k];
        xv[3] = xp[3 * XS + k];
#pragma unroll
        for (int cq = 0; cq < CQ; ++cq) {
            float4 wv = *(const float4*)(wp + (size_t)k * DOUT + cq * 4);
#pragma unroll
            for (int i = 0; i < 4; ++i) {
                acc[i][cq * 4 + 0] = fmaf(xv[i], wv.x, acc[i][cq * 4 + 0]);
                acc[i][cq * 4 + 1] = fmaf(xv[i], wv.y, acc[i][cq * 4 + 1]);
                acc[i][cq * 4 + 2] = fmaf(xv[i], wv.z, acc[i][cq * 4 + 2]);
                acc[i][cq * 4 + 3] = fmaf(xv[i], wv.w, acc[i][cq * 4 + 3]);
            }
        }
    }

#pragma unroll
    for (int i = 0; i < 4; ++i) {
        int r = row0 + rg * 4 + i;
        if (r < n) {
#pragma unroll
            for (int cq = 0; cq < CQ; ++cq) {
                float4 o = make_float4(acc[i][cq * 4 + 0], acc[i][cq * 4 + 1],
                                       acc[i][cq * 4 + 2], acc[i][cq * 4 + 3]);
                *(float4*)(h + (size_t)r * DOUT + cg * COLS + cq * 4) = o;
            }
        }
    }
}

// ---------------- CSR gather aggregation (float4 lanes) ----------------
// out[d] = h[d]*dis[d]^2 + b + sum_{s in N(d)} h[s]*dis[s]*dis[d]
template<int DOUT>
__global__ __launch_bounds__(256) void k_aggregate4(const float* __restrict__ h,
        const float* __restrict__ dis, const float* __restrict__ b,
        const int* __restrict__ off, const int* __restrict__ csr,
        float* __restrict__ out, int n) {
    constexpr int TPN = DOUT / 4;   // lanes per node
    constexpr int NPB = 256 / TPN;  // nodes per block
    int lane = threadIdx.x % TPN;
    int node = blockIdx.x * NPB + threadIdx.x / TPN;
    if (node >= n) return;
    float dd = dis[node];
    const float4* hb = (const float4*)h;
    float4 bb = ((const float4*)b)[lane];
    float4 hv = hb[(size_t)node * TPN + lane];
    float4 acc;
    float d2 = dd * dd;
    acc.x = fmaf(hv.x, d2, bb.x);
    acc.y = fmaf(hv.y, d2, bb.y);
    acc.z = fmaf(hv.z, d2, bb.z);
    acc.w = fmaf(hv.w, d2, bb.w);
    int e0 = off[node], e1 = off[node + 1];
    int e = e0;
    for (; e + 1 < e1; e += 2) {
        int s0 = csr[e], s1 = csr[e + 1];
        float w0 = dis[s0] * dd, w1 = dis[s1] * dd;
        float4 v0 = hb[(size_t)s0 * TPN + lane];
        float4 v1 = hb[(size_t)s1 * TPN + lane];
        acc.x = fmaf(v0.x, w0, acc.x); acc.y = fmaf(v0.y, w0, acc.y);
        acc.z = fmaf(v0.z, w0, acc.z); acc.w = fmaf(v0.w, w0, acc.w);
        acc.x = fmaf(v1.x, w1, acc.x); acc.y = fmaf(v1.y, w1, acc.y);
        acc.z = fmaf(v1.z, w1, acc.z); acc.w = fmaf(v1.w, w1, acc.w);
    }
    if (e < e1) {
        int s0 = csr[e];
        float w0 = dis[s0] * dd;
        float4 v0 = hb[(size_t)s0 * TPN + lane];
        acc.x = fmaf(v0.x, w0, acc.x); acc.y = fmaf(v0.y, w0, acc.y);
        acc.z = fmaf(v0.z, w0, acc.z); acc.w = fmaf(v0.w, w0, acc.w);
    }
    ((float4*)out)[(size_t)node * TPN + lane] = acc;
}

// ---------------- MLP head ----------------
__global__ void k_mlp(const float* __restrict__ xin,
                      const float* __restrict__ lw0, const float* __restrict__ lb0,
                      const float* __restrict__ lw1, const float* __restrict__ lb1,
                      const float* __restrict__ lw2, const float* __restrict__ lb2,
                      float* __restrict__ s, int n) {
    int i = blockIdx.x * blockDim.x + threadIdx.x;
    if (i >= n) return;
    float v[32];
    const float4* xp = (const float4*)(xin + (size_t)i * 32);
#pragma unroll
    for (int q = 0; q < 8; ++q) {
        float4 t = xp[q];
        v[4 * q + 0] = fmaxf(t.x, 0.f);
        v[4 * q + 1] = fmaxf(t.y, 0.f);
        v[4 * q + 2] = fmaxf(t.z, 0.f);
        v[4 * q + 3] = fmaxf(t.w, 0.f);
    }
    float a[16];
#pragma unroll
    for (int j = 0; j < 16; ++j) {
        float acc = lb0[j];
#pragma unroll
        for (int k = 0; k < 32; ++k) acc = fmaf(v[k], lw0[k * 16 + j], acc);
        a[j] = fmaxf(acc, 0.f);
    }
    float b8[8];
#pragma unroll
    for (int j = 0; j < 8; ++j) {
        float acc = lb1[j];
#pragma unroll
        for (int k = 0; k < 16; ++k) acc = fmaf(a[k], lw1[k * 8 + j], acc);
        b8[j] = fmaxf(acc, 0.f);
    }
    float z = lb2[0];
#pragma unroll
    for (int k = 0; k < 8; ++k) z = fmaf(b8[k], lw2[k], z);
    s[i] = 1.0f / (1.0f + expf(-z));
}

__global__ void k_pred(const float* __restrict__ s, const int* __restrict__ pe,
                       float* __restrict__ out, int ep) {
    int i = blockIdx.x * blockDim.x + threadIdx.x;
    if (i < ep) out[i] = s[pe[2 * i]] * s[pe[2 * i + 1]];
}

extern "C" void kernel_launch(void* const* d_in, const int* in_sizes, int n_in,
                              void* d_out, int out_size, void* d_ws, size_t ws_size,
                              hipStream_t stream) {
    const float* x   = (const float*)d_in[0];
    const int*   ei  = (const int*)d_in[1];
    const int*   pe  = (const int*)d_in[2];
    const float* cw0 = (const float*)d_in[3];
    const float* cb0 = (const float*)d_in[4];
    const float* cw1 = (const float*)d_in[5];
    const float* cb1 = (const float*)d_in[6];
    const float* cw2 = (const float*)d_in[7];
    const float* cb2 = (const float*)d_in[8];
    const float* lw0 = (const float*)d_in[9];
    const float* lb0 = (const float*)d_in[10];
    const float* lw1 = (const float*)d_in[11];
    const float* lb1 = (const float*)d_in[12];
    const float* lw2 = (const float*)d_in[13];
    const float* lb2 = (const float*)d_in[14];

    const int* src = ei;        // edge_index[0]
    const int* dst = ei + NE;   // edge_index[1]

    // workspace layout
    char* w = (char*)d_ws;
    float* dis = (float*)w;                 w += sizeof(float) * NN;
    float* A   = (float*)w;                 w += sizeof(float) * (size_t)NN * 128;
    float* B   = (float*)w;                 w += sizeof(float) * (size_t)NN * 128;
    float* sv  = (float*)w;                 w += sizeof(float) * NN;
    int*   cnt = (int*)w;                   w += sizeof(int) * NN;
    int*   off = (int*)w;                   w += sizeof(int) * (NN + 1);
    int*   cur = (int*)w;                   w += sizeof(int) * NN;
    int*   csr = (int*)w;                   w += sizeof(int) * NE;
    int*   bsum = (int*)w;                  w += sizeof(int) * 256;

    const int T = 256;
    const int NB = cdiv(NN, 256);

    // --- CSR build + normalization ---
    k_zero_i<<<cdiv(NN, T), T, 0, stream>>>(cnt, NN);
    k_count<<<cdiv(NE, T), T, 0, stream>>>(dst, cnt, NE);
    k_dis_from_cnt<<<cdiv(NN, T), T, 0, stream>>>(cnt, dis, NN);
    k_scan_local<<<NB, 256, 0, stream>>>(cnt, off, bsum, NN);
    k_scan_bsum<<<1, 256, 0, stream>>>(bsum, NB);
    k_finalize_off<<<cdiv(NN, T), T, 0, stream>>>(off, bsum, cur, NN, NE);
    k_fill<<<cdiv(NE, T), T, 0, stream>>>(src, dst, cur, csr, NE);

    // --- conv0: 128 -> 128 ---   (thread: 4 rows x 8 cols, ROWS=64)
    k_gemm_tiled<128, 128, 8, false><<<cdiv(NN, 64), 256, 0, stream>>>(x, cw0, A, NN);
    k_aggregate4<128><<<cdiv(NN, 256 / 32), 256, 0, stream>>>(A, dis, cb0, off, csr, B, NN);

    // --- conv1: 128 -> 64 (relu in) ---  (thread: 4x4, ROWS=64)
    k_gemm_tiled<128, 64, 4, true><<<cdiv(NN, 64), 256, 0, stream>>>(B, cw1, A, NN);
    k_aggregate4<64><<<cdiv(NN, 256 / 16), 256, 0, stream>>>(A, dis, cb1, off, csr, B, NN);

    // --- conv2: 64 -> 32 (relu in) ---   (thread: 4x4, ROWS=128)
    k_gemm_tiled<64, 32, 4, true><<<cdiv(NN, 128), 256, 0, stream>>>(B, cw2, A, NN);
    k_aggregate4<32><<<cdiv(NN, 256 / 8), 256, 0, stream>>>(A, dis, cb2, off, csr, B, NN);

    // --- MLP head + link prediction ---
    k_mlp<<<cdiv(NN, T), T, 0, stream>>>(B, lw0, lb0, lw1, lb1, lw2, lb2, sv, NN);
    k_pred<<<cdiv(NEP, T), T, 0, stream>>>(sv, pe, (float*)d_out, NEP);
}

// Round 4
// 347.199 us; speedup vs baseline: 8.0707x; 1.1785x over previous
//
#include <hip/hip_runtime.h>
#include <math.h>

constexpr int NN  = 50000;   // nodes
constexpr int NE  = 800000;  // edges
constexpr int NEP = 200000;  // pred edges

typedef _Float16 half4_t __attribute__((ext_vector_type(4)));

static inline int cdiv(long long a, int b) { return (int)((a + b - 1) / b); }

// ---------------- CSR build ----------------
__global__ void k_count(const int* __restrict__ dst, int* __restrict__ cnt, int e) {
    int i = blockIdx.x * blockDim.x + threadIdx.x;
    if (i < e) atomicAdd(&cnt[dst[i]], 1);
}

__global__ void k_scan_local(const int* __restrict__ cnt, int* __restrict__ off,
                             int* __restrict__ bsum, int n) {
    __shared__ int sh[256];
    int i = blockIdx.x * 256 + threadIdx.x;
    int v = (i < n) ? cnt[i] : 0;
    sh[threadIdx.x] = v;
    __syncthreads();
    for (int d = 1; d < 256; d <<= 1) {
        int t = (threadIdx.x >= d) ? sh[threadIdx.x - d] : 0;
        __syncthreads();
        sh[threadIdx.x] += t;
        __syncthreads();
    }
    if (i < n) off[i] = sh[threadIdx.x] - v;  // exclusive
    if (threadIdx.x == 255) bsum[blockIdx.x] = sh[255];
}

__global__ void k_scan_bsum(int* __restrict__ bsum, int nb) {
    __shared__ int sh[256];
    int v = (threadIdx.x < nb) ? bsum[threadIdx.x] : 0;
    sh[threadIdx.x] = v;
    __syncthreads();
    for (int d = 1; d < 256; d <<= 1) {
        int t = (threadIdx.x >= d) ? sh[threadIdx.x - d] : 0;
        __syncthreads();
        sh[threadIdx.x] += t;
        __syncthreads();
    }
    if (threadIdx.x < nb) bsum[threadIdx.x] = sh[threadIdx.x] - v;  // exclusive
}

// off/cur finalize + dis = rsqrt(deg+1)
__global__ void k_finalize_off(int* __restrict__ off, const int* __restrict__ bsum,
                               int* __restrict__ cur, const int* __restrict__ cnt,
                               float* __restrict__ dis, int n, int e) {
    int i = blockIdx.x * blockDim.x + threadIdx.x;
    if (i < n) {
        int o = off[i] + bsum[i >> 8];
        off[i] = o;
        cur[i] = o;
        dis[i] = rsqrtf((float)cnt[i] + 1.0f);
    }
    if (i == 0) off[n] = e;
}

__global__ void k_fill(const int* __restrict__ src, const int* __restrict__ dst,
                       int* __restrict__ cur, int* __restrict__ csr, int e) {
    int i = blockIdx.x * blockDim.x + threadIdx.x;
    if (i < e) {
        int d = dst[i];
        int p = atomicAdd(&cur[d], 1);
        csr[p] = src[i];
    }
}

// ---------------- register-tiled GEMM: g = dis * ((relu?)x @ W), fp16 out ----------------
// 256 threads; block computes ROWS x DOUT. Thread: 4 rows x COLS cols.
template<int K, int DOUT, int COLS, bool RELU_IN>
__global__ __launch_bounds__(256) void k_gemm_tiled(const float* __restrict__ x,
        const float* __restrict__ W, const float* __restrict__ dis,
        half4_t* __restrict__ g, int n) {
    constexpr int CG   = DOUT / COLS;  // column groups
    constexpr int RG   = 256 / CG;     // row groups
    constexpr int ROWS = 4 * RG;       // rows per block
    constexpr int XS   = K + 1;        // padded LDS stride
    constexpr int CQ   = COLS / 4;
    __shared__ float sX[ROWS * XS];

    const int tid  = threadIdx.x;
    const int row0 = blockIdx.x * ROWS;

    constexpr int NLD = ROWS * K / 4 / 256;
#pragma unroll
    for (int i = 0; i < NLD; ++i) {
        int idx = tid + i * 256;
        int r   = idx / (K / 4);
        int kq  = (idx - r * (K / 4)) * 4;
        float4 v = make_float4(0.f, 0.f, 0.f, 0.f);
        if (row0 + r < n) v = *(const float4*)(x + (size_t)(row0 + r) * K + kq);
        if (RELU_IN) {
            v.x = fmaxf(v.x, 0.f); v.y = fmaxf(v.y, 0.f);
            v.z = fmaxf(v.z, 0.f); v.w = fmaxf(v.w, 0.f);
        }
        float* p = sX + r * XS + kq;
        p[0] = v.x; p[1] = v.y; p[2] = v.z; p[3] = v.w;
    }
    __syncthreads();

    const int cg = tid % CG;
    const int rg = tid / CG;
    const float* xp = sX + rg * 4 * XS;
    const float* wp = W + cg * COLS;

    float acc[4][COLS];
#pragma unroll
    for (int i = 0; i < 4; ++i)
#pragma unroll
        for (int c = 0; c < COLS; ++c) acc[i][c] = 0.f;

#pragma unroll 4
    for (int k = 0; k < K; ++k) {
        float xv[4];
        xv[0] = xp[k];
        xv[1] = xp[XS + k];
        xv[2] = xp[2 * XS + k];
        xv[3] = xp[3 * XS + k];
#pragma unroll
        for (int cq = 0; cq < CQ; ++cq) {
            float4 wv = *(const float4*)(wp + (size_t)k * DOUT + cq * 4);
#pragma unroll
            for (int i = 0; i < 4; ++i) {
                acc[i][cq * 4 + 0] = fmaf(xv[i], wv.x, acc[i][cq * 4 + 0]);
                acc[i][cq * 4 + 1] = fmaf(xv[i], wv.y, acc[i][cq * 4 + 1]);
                acc[i][cq * 4 + 2] = fmaf(xv[i], wv.z, acc[i][cq * 4 + 2]);
                acc[i][cq * 4 + 3] = fmaf(xv[i], wv.w, acc[i][cq * 4 + 3]);
            }
        }
    }

#pragma unroll
    for (int i = 0; i < 4; ++i) {
        int r = row0 + rg * 4 + i;
        if (r < n) {
            float s = dis[r];
#pragma unroll
            for (int cq = 0; cq < CQ; ++cq) {
                half4_t o;
                o.x = (_Float16)(acc[i][cq * 4 + 0] * s);
                o.y = (_Float16)(acc[i][cq * 4 + 1] * s);
                o.z = (_Float16)(acc[i][cq * 4 + 2] * s);
                o.w = (_Float16)(acc[i][cq * 4 + 3] * s);
                g[(size_t)r * (DOUT / 4) + cg * CQ + cq] = o;
            }
        }
    }
}

// ---------------- CSR gather aggregation (fp16 messages) ----------------
// out[d] = dis[d] * (g[d] + sum_{s in N(d)} g[s]) + b,  g = dis*h in fp16
template<int DOUT>
__global__ __launch_bounds__(256) void k_aggregate_h(const half4_t* __restrict__ g,
        const float* __restrict__ dis, const float* __restrict__ b,
        const int* __restrict__ off, const int* __restrict__ csr,
        float* __restrict__ out, int n) {
    constexpr int TPN = DOUT / 4;   // lanes per node (half4 each)
    constexpr int NPB = 256 / TPN;  // nodes per block
    int lane = threadIdx.x % TPN;
    int node = blockIdx.x * NPB + threadIdx.x / TPN;
    if (node >= n) return;
    float dd = dis[node];
    half4_t hv = g[(size_t)node * TPN + lane];
    float ax = (float)hv.x, ay = (float)hv.y, az = (float)hv.z, aw = (float)hv.w;
    int e0 = off[node], e1 = off[node + 1];
    int e = e0;
    for (; e + 3 < e1; e += 4) {
        int s0 = csr[e], s1 = csr[e + 1], s2 = csr[e + 2], s3 = csr[e + 3];
        half4_t v0 = g[(size_t)s0 * TPN + lane];
        half4_t v1 = g[(size_t)s1 * TPN + lane];
        half4_t v2 = g[(size_t)s2 * TPN + lane];
        half4_t v3 = g[(size_t)s3 * TPN + lane];
        ax += (float)v0.x; ay += (float)v0.y; az += (float)v0.z; aw += (float)v0.w;
        ax += (float)v1.x; ay += (float)v1.y; az += (float)v1.z; aw += (float)v1.w;
        ax += (float)v2.x; ay += (float)v2.y; az += (float)v2.z; aw += (float)v2.w;
        ax += (float)v3.x; ay += (float)v3.y; az += (float)v3.z; aw += (float)v3.w;
    }
    for (; e < e1; ++e) {
        int s0 = csr[e];
        half4_t v0 = g[(size_t)s0 * TPN + lane];
        ax += (float)v0.x; ay += (float)v0.y; az += (float)v0.z; aw += (float)v0.w;
    }
    float4 bb = ((const float4*)b)[lane];
    float4 o;
    o.x = fmaf(ax, dd, bb.x);
    o.y = fmaf(ay, dd, bb.y);
    o.z = fmaf(az, dd, bb.z);
    o.w = fmaf(aw, dd, bb.w);
    ((float4*)out)[(size_t)node * TPN + lane] = o;
}

// ---------------- MLP head ----------------
__global__ void k_mlp(const float* __restrict__ xin,
                      const float* __restrict__ lw0, const float* __restrict__ lb0,
                      const float* __restrict__ lw1, const float* __restrict__ lb1,
                      const float* __restrict__ lw2, const float* __restrict__ lb2,
                      float* __restrict__ s, int n) {
    int i = blockIdx.x * blockDim.x + threadIdx.x;
    if (i >= n) return;
    float v[32];
    const float4* xp = (const float4*)(xin + (size_t)i * 32);
#pragma unroll
    for (int q = 0; q < 8; ++q) {
        float4 t = xp[q];
        v[4 * q + 0] = fmaxf(t.x, 0.f);
        v[4 * q + 1] = fmaxf(t.y, 0.f);
        v[4 * q + 2] = fmaxf(t.z, 0.f);
        v[4 * q + 3] = fmaxf(t.w, 0.f);
    }
    float a[16];
#pragma unroll
    for (int j = 0; j < 16; ++j) {
        float acc = lb0[j];
#pragma unroll
        for (int k = 0; k < 32; ++k) acc = fmaf(v[k], lw0[k * 16 + j], acc);
        a[j] = fmaxf(acc, 0.f);
    }
    float b8[8];
#pragma unroll
    for (int j = 0; j < 8; ++j) {
        float acc = lb1[j];
#pragma unroll
        for (int k = 0; k < 16; ++k) acc = fmaf(a[k], lw1[k * 8 + j], acc);
        b8[j] = fmaxf(acc, 0.f);
    }
    float z = lb2[0];
#pragma unroll
    for (int k = 0; k < 8; ++k) z = fmaf(b8[k], lw2[k], z);
    s[i] = 1.0f / (1.0f + expf(-z));
}

__global__ void k_pred(const float* __restrict__ s, const int* __restrict__ pe,
                       float* __restrict__ out, int ep) {
    int i = blockIdx.x * blockDim.x + threadIdx.x;
    if (i < ep) out[i] = s[pe[2 * i]] * s[pe[2 * i + 1]];
}

extern "C" void kernel_launch(void* const* d_in, const int* in_sizes, int n_in,
                              void* d_out, int out_size, void* d_ws, size_t ws_size,
                              hipStream_t stream) {
    const float* x   = (const float*)d_in[0];
    const int*   ei  = (const int*)d_in[1];
    const int*   pe  = (const int*)d_in[2];
    const float* cw0 = (const float*)d_in[3];
    const float* cb0 = (const float*)d_in[4];
    const float* cw1 = (const float*)d_in[5];
    const float* cb1 = (const float*)d_in[6];
    const float* cw2 = (const float*)d_in[7];
    const float* cb2 = (const float*)d_in[8];
    const float* lw0 = (const float*)d_in[9];
    const float* lb0 = (const float*)d_in[10];
    const float* lw1 = (const float*)d_in[11];
    const float* lb1 = (const float*)d_in[12];
    const float* lw2 = (const float*)d_in[13];
    const float* lb2 = (const float*)d_in[14];

    const int* src = ei;        // edge_index[0]
    const int* dst = ei + NE;   // edge_index[1]

    // workspace layout
    char* w = (char*)d_ws;
    float*   dis = (float*)w;    w += sizeof(float) * NN;
    half4_t* A   = (half4_t*)w;  w += sizeof(_Float16) * (size_t)NN * 128;  // fp16 messages
    float*   B   = (float*)w;    w += sizeof(float) * (size_t)NN * 128;     // fp32 activations
    float*   sv  = (float*)w;    w += sizeof(float) * NN;
    int*     cnt = (int*)w;      w += sizeof(int) * NN;
    int*     off = (int*)w;      w += sizeof(int) * (NN + 1);
    int*     cur = (int*)w;      w += sizeof(int) * NN;
    int*     csr = (int*)w;      w += sizeof(int) * NE;
    int*     bsum = (int*)w;     w += sizeof(int) * 256;

    const int T = 256;
    const int NB = cdiv(NN, 256);

    // --- CSR build + normalization ---
    hipMemsetAsync(cnt, 0, sizeof(int) * NN, stream);
    k_count<<<cdiv(NE, T), T, 0, stream>>>(dst, cnt, NE);
    k_scan_local<<<NB, 256, 0, stream>>>(cnt, off, bsum, NN);
    k_scan_bsum<<<1, 256, 0, stream>>>(bsum, NB);
    k_finalize_off<<<cdiv(NN, T), T, 0, stream>>>(off, bsum, cur, cnt, dis, NN, NE);
    k_fill<<<cdiv(NE, T), T, 0, stream>>>(src, dst, cur, csr, NE);

    // --- conv0: 128 -> 128 ---
    k_gemm_tiled<128, 128, 8, false><<<cdiv(NN, 64), 256, 0, stream>>>(x, cw0, dis, A, NN);
    k_aggregate_h<128><<<cdiv(NN, 8), 256, 0, stream>>>(A, dis, cb0, off, csr, B, NN);

    // --- conv1: 128 -> 64 (relu in) ---
    k_gemm_tiled<128, 64, 4, true><<<cdiv(NN, 64), 256, 0, stream>>>(B, cw1, dis, A, NN);
    k_aggregate_h<64><<<cdiv(NN, 16), 256, 0, stream>>>(A, dis, cb1, off, csr, B, NN);

    // --- conv2: 64 -> 32 (relu in) ---
    k_gemm_tiled<64, 32, 4, true><<<cdiv(NN, 128), 256, 0, stream>>>(B, cw2, dis, A, NN);
    k_aggregate_h<32><<<cdiv(NN, 32), 256, 0, stream>>>(A, dis, cb2, off, csr, B, NN);

    // --- MLP head + link prediction ---
    k_mlp<<<cdiv(NN, T), T, 0, stream>>>(B, lw0, lb0, lw1, lb1, lw2, lb2, sv, NN);
    k_pred<<<cdiv(NEP, T), T, 0, stream>>>(sv, pe, (float*)d_out, NEP);
}

// Round 5
// 343.511 us; speedup vs baseline: 8.1573x; 1.0107x over previous
//
#include <hip/hip_runtime.h>
#include <math.h>

constexpr int NN  = 50000;   // nodes (< 65536 -> csr fits in ushort)
constexpr int NE  = 800000;  // edges
constexpr int NEP = 200000;  // pred edges

typedef _Float16 half4_t __attribute__((ext_vector_type(4)));

static inline int cdiv(long long a, int b) { return (int)((a + b - 1) / b); }

// ---------------- CSR build ----------------
__global__ void k_count(const int* __restrict__ dst, int* __restrict__ cnt, int e) {
    int i = blockIdx.x * blockDim.x + threadIdx.x;
    if (i < e) atomicAdd(&cnt[dst[i]], 1);
}

__global__ void k_scan_local(const int* __restrict__ cnt, int* __restrict__ off,
                             int* __restrict__ bsum, int n) {
    __shared__ int sh[256];
    int i = blockIdx.x * 256 + threadIdx.x;
    int v = (i < n) ? cnt[i] : 0;
    sh[threadIdx.x] = v;
    __syncthreads();
    for (int d = 1; d < 256; d <<= 1) {
        int t = (threadIdx.x >= d) ? sh[threadIdx.x - d] : 0;
        __syncthreads();
        sh[threadIdx.x] += t;
        __syncthreads();
    }
    if (i < n) off[i] = sh[threadIdx.x] - v;  // exclusive
    if (threadIdx.x == 255) bsum[blockIdx.x] = sh[255];
}

__global__ void k_scan_bsum(int* __restrict__ bsum, int nb) {
    __shared__ int sh[256];
    int v = (threadIdx.x < nb) ? bsum[threadIdx.x] : 0;
    sh[threadIdx.x] = v;
    __syncthreads();
    for (int d = 1; d < 256; d <<= 1) {
        int t = (threadIdx.x >= d) ? sh[threadIdx.x - d] : 0;
        __syncthreads();
        sh[threadIdx.x] += t;
        __syncthreads();
    }
    if (threadIdx.x < nb) bsum[threadIdx.x] = sh[threadIdx.x] - v;  // exclusive
}

// off/cur finalize + dis = rsqrt(deg+1)
__global__ void k_finalize_off(int* __restrict__ off, const int* __restrict__ bsum,
                               int* __restrict__ cur, const int* __restrict__ cnt,
                               float* __restrict__ dis, int n, int e) {
    int i = blockIdx.x * blockDim.x + threadIdx.x;
    if (i < n) {
        int o = off[i] + bsum[i >> 8];
        off[i] = o;
        cur[i] = o;
        dis[i] = rsqrtf((float)cnt[i] + 1.0f);
    }
    if (i == 0) off[n] = e;
}

__global__ void k_fill(const int* __restrict__ src, const int* __restrict__ dst,
                       int* __restrict__ cur, unsigned short* __restrict__ csr, int e) {
    int i = blockIdx.x * blockDim.x + threadIdx.x;
    if (i < e) {
        int d = dst[i];
        int p = atomicAdd(&cur[d], 1);
        csr[p] = (unsigned short)src[i];
    }
}

// ---------------- register-tiled GEMM: g = dis * ((relu?)x @ W), fp16 out ----------------
// 256 threads; block computes ROWS x DOUT; thread: 4 rows x COLS cols.
// Output written channel-slice-major: SPLIT slices, each n x (DOUT/SPLIT) fp16.
template<int K, int DOUT, int COLS, bool RELU_IN, int SPLIT>
__global__ __launch_bounds__(256) void k_gemm_tiled(const float* __restrict__ x,
        const float* __restrict__ W, const float* __restrict__ dis,
        half4_t* __restrict__ g, int n) {
    constexpr int CG   = DOUT / COLS;      // column groups
    constexpr int RG   = 256 / CG;         // row groups
    constexpr int ROWS = 4 * RG;           // rows per block
    constexpr int XS   = K + 1;            // padded LDS stride
    constexpr int CQ   = COLS / 4;
    constexpr int W4   = DOUT / 4 / SPLIT; // half4 per slice row
    __shared__ float sX[ROWS * XS];

    const int tid  = threadIdx.x;
    const int row0 = blockIdx.x * ROWS;

    constexpr int NLD = ROWS * K / 4 / 256;
#pragma unroll
    for (int i = 0; i < NLD; ++i) {
        int idx = tid + i * 256;
        int r   = idx / (K / 4);
        int kq  = (idx - r * (K / 4)) * 4;
        float4 v = make_float4(0.f, 0.f, 0.f, 0.f);
        if (row0 + r < n) v = *(const float4*)(x + (size_t)(row0 + r) * K + kq);
        if (RELU_IN) {
            v.x = fmaxf(v.x, 0.f); v.y = fmaxf(v.y, 0.f);
            v.z = fmaxf(v.z, 0.f); v.w = fmaxf(v.w, 0.f);
        }
        float* p = sX + r * XS + kq;
        p[0] = v.x; p[1] = v.y; p[2] = v.z; p[3] = v.w;
    }
    __syncthreads();

    const int cg = tid % CG;
    const int rg = tid / CG;
    const float* xp = sX + rg * 4 * XS;
    const float* wp = W + cg * COLS;

    float acc[4][COLS];
#pragma unroll
    for (int i = 0; i < 4; ++i)
#pragma unroll
        for (int c = 0; c < COLS; ++c) acc[i][c] = 0.f;

#pragma unroll 4
    for (int k = 0; k < K; ++k) {
        float xv[4];
        xv[0] = xp[k];
        xv[1] = xp[XS + k];
        xv[2] = xp[2 * XS + k];
        xv[3] = xp[3 * XS + k];
#pragma unroll
        for (int cq = 0; cq < CQ; ++cq) {
            float4 wv = *(const float4*)(wp + (size_t)k * DOUT + cq * 4);
#pragma unroll
            for (int i = 0; i < 4; ++i) {
                acc[i][cq * 4 + 0] = fmaf(xv[i], wv.x, acc[i][cq * 4 + 0]);
                acc[i][cq * 4 + 1] = fmaf(xv[i], wv.y, acc[i][cq * 4 + 1]);
                acc[i][cq * 4 + 2] = fmaf(xv[i], wv.z, acc[i][cq * 4 + 2]);
                acc[i][cq * 4 + 3] = fmaf(xv[i], wv.w, acc[i][cq * 4 + 3]);
            }
        }
    }

#pragma unroll
    for (int i = 0; i < 4; ++i) {
        int r = row0 + rg * 4 + i;
        if (r < n) {
            float s = dis[r];
#pragma unroll
            for (int cq = 0; cq < CQ; ++cq) {
                half4_t o;
                o.x = (_Float16)(acc[i][cq * 4 + 0] * s);
                o.y = (_Float16)(acc[i][cq * 4 + 1] * s);
                o.z = (_Float16)(acc[i][cq * 4 + 2] * s);
                o.w = (_Float16)(acc[i][cq * 4 + 3] * s);
                int c     = cg * CQ + cq;        // global half4 column
                int slice = c / W4;
                int local = c - slice * W4;
                g[(size_t)slice * n * W4 + (size_t)r * W4 + local] = o;
            }
        }
    }
}

// ---------------- CSR gather aggregation over one channel slice ----------------
// out[d*stride4 .. ] = dis[d] * (g[d] + sum_{s in N(d)} g[s]) + b
// g: n x (DC) fp16 slice; out/b pre-offset to this slice's column window.
template<int DC>
__global__ __launch_bounds__(256) void k_aggregate_h(const half4_t* __restrict__ g,
        const float* __restrict__ dis, const float* __restrict__ b,
        const int* __restrict__ off, const unsigned short* __restrict__ csr,
        float* __restrict__ out, int outStride4, int n) {
    constexpr int TPN = DC / 4;     // half4 lanes per node
    constexpr int NPB = 256 / TPN;  // nodes per block
    int lane = threadIdx.x % TPN;
    int node = blockIdx.x * NPB + threadIdx.x / TPN;
    if (node >= n) return;
    float dd = dis[node];
    half4_t hv = g[(size_t)node * TPN + lane];
    float ax = (float)hv.x, ay = (float)hv.y, az = (float)hv.z, aw = (float)hv.w;
    int e0 = off[node], e1 = off[node + 1];
    int e = e0;
    for (; e + 3 < e1; e += 4) {
        int s0 = csr[e], s1 = csr[e + 1], s2 = csr[e + 2], s3 = csr[e + 3];
        half4_t v0 = g[(size_t)s0 * TPN + lane];
        half4_t v1 = g[(size_t)s1 * TPN + lane];
        half4_t v2 = g[(size_t)s2 * TPN + lane];
        half4_t v3 = g[(size_t)s3 * TPN + lane];
        ax += (float)v0.x; ay += (float)v0.y; az += (float)v0.z; aw += (float)v0.w;
        ax += (float)v1.x; ay += (float)v1.y; az += (float)v1.z; aw += (float)v1.w;
        ax += (float)v2.x; ay += (float)v2.y; az += (float)v2.z; aw += (float)v2.w;
        ax += (float)v3.x; ay += (float)v3.y; az += (float)v3.z; aw += (float)v3.w;
    }
    for (; e < e1; ++e) {
        int s0 = csr[e];
        half4_t v0 = g[(size_t)s0 * TPN + lane];
        ax += (float)v0.x; ay += (float)v0.y; az += (float)v0.z; aw += (float)v0.w;
    }
    float4 bb = ((const float4*)b)[lane];
    float4 o;
    o.x = fmaf(ax, dd, bb.x);
    o.y = fmaf(ay, dd, bb.y);
    o.z = fmaf(az, dd, bb.z);
    o.w = fmaf(aw, dd, bb.w);
    ((float4*)out)[(size_t)node * outStride4 + lane] = o;
}

// ---------------- MLP head ----------------
__global__ void k_mlp(const float* __restrict__ xin,
                      const float* __restrict__ lw0, const float* __restrict__ lb0,
                      const float* __restrict__ lw1, const float* __restrict__ lb1,
                      const float* __restrict__ lw2, const float* __restrict__ lb2,
                      float* __restrict__ s, int n) {
    int i = blockIdx.x * blockDim.x + threadIdx.x;
    if (i >= n) return;
    float v[32];
    const float4* xp = (const float4*)(xin + (size_t)i * 32);
#pragma unroll
    for (int q = 0; q < 8; ++q) {
        float4 t = xp[q];
        v[4 * q + 0] = fmaxf(t.x, 0.f);
        v[4 * q + 1] = fmaxf(t.y, 0.f);
        v[4 * q + 2] = fmaxf(t.z, 0.f);
        v[4 * q + 3] = fmaxf(t.w, 0.f);
    }
    float a[16];
#pragma unroll
    for (int j = 0; j < 16; ++j) {
        float acc = lb0[j];
#pragma unroll
        for (int k = 0; k < 32; ++k) acc = fmaf(v[k], lw0[k * 16 + j], acc);
        a[j] = fmaxf(acc, 0.f);
    }
    float b8[8];
#pragma unroll
    for (int j = 0; j < 8; ++j) {
        float acc = lb1[j];
#pragma unroll
        for (int k = 0; k < 16; ++k) acc = fmaf(a[k], lw1[k * 8 + j], acc);
        b8[j] = fmaxf(acc, 0.f);
    }
    float z = lb2[0];
#pragma unroll
    for (int k = 0; k < 8; ++k) z = fmaf(b8[k], lw2[k], z);
    s[i] = 1.0f / (1.0f + expf(-z));
}

__global__ void k_pred(const float* __restrict__ s, const int* __restrict__ pe,
                       float* __restrict__ out, int ep) {
    int i = blockIdx.x * blockDim.x + threadIdx.x;
    if (i < ep) out[i] = s[pe[2 * i]] * s[pe[2 * i + 1]];
}

extern "C" void kernel_launch(void* const* d_in, const int* in_sizes, int n_in,
                              void* d_out, int out_size, void* d_ws, size_t ws_size,
                              hipStream_t stream) {
    const float* x   = (const float*)d_in[0];
    const int*   ei  = (const int*)d_in[1];
    const int*   pe  = (const int*)d_in[2];
    const float* cw0 = (const float*)d_in[3];
    const float* cb0 = (const float*)d_in[4];
    const float* cw1 = (const float*)d_in[5];
    const float* cb1 = (const float*)d_in[6];
    const float* cw2 = (const float*)d_in[7];
    const float* cb2 = (const float*)d_in[8];
    const float* lw0 = (const float*)d_in[9];
    const float* lb0 = (const float*)d_in[10];
    const float* lw1 = (const float*)d_in[11];
    const float* lb1 = (const float*)d_in[12];
    const float* lw2 = (const float*)d_in[13];
    const float* lb2 = (const float*)d_in[14];

    const int* src = ei;        // edge_index[0]
    const int* dst = ei + NE;   // edge_index[1]

    // workspace layout
    char* w = (char*)d_ws;
    float*          dis = (float*)w;           w += sizeof(float) * NN;
    half4_t*        A   = (half4_t*)w;         w += sizeof(_Float16) * (size_t)NN * 128;
    float*          B   = (float*)w;           w += sizeof(float) * (size_t)NN * 128;
    float*          sv  = (float*)w;           w += sizeof(float) * NN;
    int*            cnt = (int*)w;             w += sizeof(int) * NN;
    int*            off = (int*)w;             w += sizeof(int) * (NN + 1);
    int*            cur = (int*)w;             w += sizeof(int) * NN;
    unsigned short* csr = (unsigned short*)w;  w += sizeof(unsigned short) * NE;
    int*            bsum = (int*)w;            w += sizeof(int) * 256;

    const int T = 256;
    const int NB = cdiv(NN, 256);

    // --- CSR build + normalization ---
    hipMemsetAsync(cnt, 0, sizeof(int) * NN, stream);
    k_count<<<cdiv(NE, T), T, 0, stream>>>(dst, cnt, NE);
    k_scan_local<<<NB, 256, 0, stream>>>(cnt, off, bsum, NN);
    k_scan_bsum<<<1, 256, 0, stream>>>(bsum, NB);
    k_finalize_off<<<cdiv(NN, T), T, 0, stream>>>(off, bsum, cur, cnt, dis, NN, NE);
    k_fill<<<cdiv(NE, T), T, 0, stream>>>(src, dst, cur, csr, NE);

    // --- conv0: 128 -> 128, messages split into 2 x 64-ch slices (6.4 MB each) ---
    k_gemm_tiled<128, 128, 8, false, 2><<<cdiv(NN, 64), 256, 0, stream>>>(x, cw0, dis, A, NN);
    k_aggregate_h<64><<<cdiv(NN, 16), 256, 0, stream>>>(A,                      dis, cb0,      off, csr, B,      32, NN);
    k_aggregate_h<64><<<cdiv(NN, 16), 256, 0, stream>>>(A + (size_t)NN * 16,    dis, cb0 + 64, off, csr, B + 64, 32, NN);

    // --- conv1: 128 -> 64, messages split into 2 x 32-ch slices (3.2 MB each) ---
    k_gemm_tiled<128, 64, 4, true, 2><<<cdiv(NN, 64), 256, 0, stream>>>(B, cw1, dis, A, NN);
    k_aggregate_h<32><<<cdiv(NN, 32), 256, 0, stream>>>(A,                      dis, cb1,      off, csr, B,      16, NN);
    k_aggregate_h<32><<<cdiv(NN, 32), 256, 0, stream>>>(A + (size_t)NN * 8,     dis, cb1 + 32, off, csr, B + 32, 16, NN);

    // --- conv2: 64 -> 32, single 32-ch slice (3.2 MB) ---
    k_gemm_tiled<64, 32, 4, true, 1><<<cdiv(NN, 128), 256, 0, stream>>>(B, cw2, dis, A, NN);
    k_aggregate_h<32><<<cdiv(NN, 32), 256, 0, stream>>>(A, dis, cb2, off, csr, B, 8, NN);

    // --- MLP head + link prediction ---
    k_mlp<<<cdiv(NN, T), T, 0, stream>>>(B, lw0, lb0, lw1, lb1, lw2, lb2, sv, NN);
    k_pred<<<cdiv(NEP, T), T, 0, stream>>>(sv, pe, (float*)d_out, NEP);
}

// Round 6
// 315.986 us; speedup vs baseline: 8.8679x; 1.0871x over previous
//
#include <hip/hip_runtime.h>
#include <math.h>

constexpr int NN  = 50000;   // nodes (< 65536 -> csr fits in ushort)
constexpr int NP  = 50048;   // padded rows (multiple of 128)
constexpr int NE  = 800000;  // edges
constexpr int NEP = 200000;  // pred edges

typedef _Float16 half4_t __attribute__((ext_vector_type(4)));
typedef _Float16 half8_t __attribute__((ext_vector_type(8)));
typedef float    float4_t __attribute__((ext_vector_type(4)));

static inline int cdiv(long long a, int b) { return (int)((a + b - 1) / b); }

// ---------------- CSR build ----------------
__global__ void k_count(const int* __restrict__ dst, int* __restrict__ cnt, int e) {
    int i = blockIdx.x * blockDim.x + threadIdx.x;
    if (i < e) atomicAdd(&cnt[dst[i]], 1);
}

__global__ void k_scan_local(const int* __restrict__ cnt, int* __restrict__ off,
                             int* __restrict__ bsum, int n) {
    __shared__ int sh[256];
    int i = blockIdx.x * 256 + threadIdx.x;
    int v = (i < n) ? cnt[i] : 0;
    sh[threadIdx.x] = v;
    __syncthreads();
    for (int d = 1; d < 256; d <<= 1) {
        int t = (threadIdx.x >= d) ? sh[threadIdx.x - d] : 0;
        __syncthreads();
        sh[threadIdx.x] += t;
        __syncthreads();
    }
    if (i < n) off[i] = sh[threadIdx.x] - v;  // exclusive
    if (threadIdx.x == 255) bsum[blockIdx.x] = sh[255];
}

__global__ void k_scan_bsum(int* __restrict__ bsum, int nb) {
    __shared__ int sh[256];
    int v = (threadIdx.x < nb) ? bsum[threadIdx.x] : 0;
    sh[threadIdx.x] = v;
    __syncthreads();
    for (int d = 1; d < 256; d <<= 1) {
        int t = (threadIdx.x >= d) ? sh[threadIdx.x - d] : 0;
        __syncthreads();
        sh[threadIdx.x] += t;
        __syncthreads();
    }
    if (threadIdx.x < nb) bsum[threadIdx.x] = sh[threadIdx.x] - v;  // exclusive
}

__global__ void k_finalize_off(int* __restrict__ off, const int* __restrict__ bsum,
                               int* __restrict__ cur, const int* __restrict__ cnt,
                               float* __restrict__ dis, int n, int e) {
    int i = blockIdx.x * blockDim.x + threadIdx.x;
    if (i < n) {
        int o = off[i] + bsum[i >> 8];
        off[i] = o;
        cur[i] = o;
        dis[i] = rsqrtf((float)cnt[i] + 1.0f);
    }
    if (i == 0) off[n] = e;
}

__global__ void k_fill(const int* __restrict__ src, const int* __restrict__ dst,
                       int* __restrict__ cur, unsigned short* __restrict__ csr, int e) {
    int i = blockIdx.x * blockDim.x + threadIdx.x;
    if (i < e) {
        int d = dst[i];
        int p = atomicAdd(&cur[d], 1);
        csr[p] = (unsigned short)src[i];
    }
}

// ---------------- prep: x fp32 -> fp16 row-major ----------------
__global__ void k_x2h(const float* __restrict__ x, half4_t* __restrict__ X, long long n4) {
    long long i = (long long)blockIdx.x * blockDim.x + threadIdx.x;
    if (i >= n4) return;
    float4 v = ((const float4*)x)[i];
    half4_t o;
    o.x = (_Float16)v.x; o.y = (_Float16)v.y; o.z = (_Float16)v.z; o.w = (_Float16)v.w;
    X[i] = o;
}

// ---------------- prep: W (KxN fp32) -> WT (NxK fp16) ----------------
template<int K, int N>
__global__ void k_wprep(const float* __restrict__ W, _Float16* __restrict__ WT) {
    int idx = blockIdx.x * blockDim.x + threadIdx.x;
    if (idx >= K * N) return;
    int k = idx / N, n = idx - k * N;
    WT[(size_t)n * K + k] = (_Float16)W[idx];
}

// ---------------- MFMA GEMM: g = dis * (X @ WT^T), fp16 in/out ----------------
// X: NP x K fp16 row-major. WT: DOUT x K fp16 (pre-transposed W).
// Output: prescaled fp16 messages in SPLIT channel slices (n x DOUT/SPLIT each).
// Wave tile: 32 rows x NC cols; block = 4 waves.
template<int K, int DOUT, int SPLIT>
__global__ __launch_bounds__(256) void k_gemm_mfma(const _Float16* __restrict__ X,
        const _Float16* __restrict__ WT, const float* __restrict__ dis,
        _Float16* __restrict__ g, int n) {
    constexpr int CW = (DOUT >= 128) ? 2 : 1;  // col wave-groups
    constexpr int RW = 4 / CW;                 // row wave-groups
    constexpr int NC = DOUT / CW;              // cols per wave
    constexpr int NT = NC / 16;                // 16-col tiles per wave
    constexpr int KT = K / 32;                 // K steps
    constexpr int MT = 2;                      // 16-row tiles per wave (32 rows)
    constexpr int BR = RW * 32;                // rows per block
    constexpr int SW = DOUT / SPLIT;           // slice width (fp16 elems)

    const int tid  = threadIdx.x;
    const int L    = tid & 63;
    const int w    = tid >> 6;
    const int wc   = w % CW;
    const int wr   = w / CW;
    const int r0   = blockIdx.x * BR + wr * 32;
    const int c0   = wc * NC;
    const int quad = L >> 4;
    const int lm   = L & 15;

    float4_t acc[MT][NT];
#pragma unroll
    for (int mt = 0; mt < MT; ++mt)
#pragma unroll
        for (int nt = 0; nt < NT; ++nt) acc[mt][nt] = (float4_t){0.f, 0.f, 0.f, 0.f};

#pragma unroll
    for (int kt = 0; kt < KT; ++kt) {
        half8_t a[MT], b[NT];
#pragma unroll
        for (int mt = 0; mt < MT; ++mt)
            a[mt] = *(const half8_t*)(X + (size_t)(r0 + mt * 16 + lm) * K + kt * 32 + quad * 8);
#pragma unroll
        for (int nt = 0; nt < NT; ++nt)
            b[nt] = *(const half8_t*)(WT + (size_t)(c0 + nt * 16 + lm) * K + kt * 32 + quad * 8);
#pragma unroll
        for (int mt = 0; mt < MT; ++mt)
#pragma unroll
            for (int nt = 0; nt < NT; ++nt)
                acc[mt][nt] = __builtin_amdgcn_mfma_f32_16x16x32_f16(a[mt], b[nt], acc[mt][nt], 0, 0, 0);
    }

    // epilogue: D[row=quad*4+reg][col=lm], scale by dis[row], store fp16 slices
#pragma unroll
    for (int mt = 0; mt < MT; ++mt) {
        int rb = r0 + mt * 16 + quad * 4;
        float dv[4];
        *(float4*)dv = *(const float4*)(dis + rb);
#pragma unroll
        for (int nt = 0; nt < NT; ++nt) {
            int c     = c0 + nt * 16 + lm;
            int slice = c / SW;
            int cl    = c - slice * SW;
            _Float16* gp = g + (size_t)slice * n * SW + cl;
#pragma unroll
            for (int reg = 0; reg < 4; ++reg) {
                int r = rb + reg;
                if (r < n) gp[(size_t)r * SW] = (_Float16)(acc[mt][nt][reg] * dv[reg]);
                gp += 0;  // keep gp; row advances via r*SW indexing
            }
        }
    }
}

// ---------------- CSR gather aggregation over one channel slice ----------------
// acc = g[d] + sum_{s in N(d)} g[s];  out = dis[d]*acc + b
// HOUT: write relu(out) as half4 (next layer's GEMM input); else float4 raw.
template<int DC, bool HOUT>
__global__ __launch_bounds__(256) void k_aggregate_h(const half4_t* __restrict__ g,
        const float* __restrict__ dis, const float* __restrict__ b,
        const int* __restrict__ off, const unsigned short* __restrict__ csr,
        void* __restrict__ out, int stride4, int n) {
    constexpr int TPN = DC / 4;     // half4 lanes per node
    constexpr int NPB = 256 / TPN;  // nodes per block
    int lane = threadIdx.x % TPN;
    int node = blockIdx.x * NPB + threadIdx.x / TPN;
    if (node >= n) return;
    float dd = dis[node];
    half4_t hv = g[(size_t)node * TPN + lane];
    float ax = (float)hv.x, ay = (float)hv.y, az = (float)hv.z, aw = (float)hv.w;
    int e0 = off[node], e1 = off[node + 1];
    int e = e0;
    for (; e + 3 < e1; e += 4) {
        int s0 = csr[e], s1 = csr[e + 1], s2 = csr[e + 2], s3 = csr[e + 3];
        half4_t v0 = g[(size_t)s0 * TPN + lane];
        half4_t v1 = g[(size_t)s1 * TPN + lane];
        half4_t v2 = g[(size_t)s2 * TPN + lane];
        half4_t v3 = g[(size_t)s3 * TPN + lane];
        ax += (float)v0.x; ay += (float)v0.y; az += (float)v0.z; aw += (float)v0.w;
        ax += (float)v1.x; ay += (float)v1.y; az += (float)v1.z; aw += (float)v1.w;
        ax += (float)v2.x; ay += (float)v2.y; az += (float)v2.z; aw += (float)v2.w;
        ax += (float)v3.x; ay += (float)v3.y; az += (float)v3.z; aw += (float)v3.w;
    }
    for (; e < e1; ++e) {
        int s0 = csr[e];
        half4_t v0 = g[(size_t)s0 * TPN + lane];
        ax += (float)v0.x; ay += (float)v0.y; az += (float)v0.z; aw += (float)v0.w;
    }
    float4 bb = ((const float4*)b)[lane];
    float ox = fmaf(ax, dd, bb.x);
    float oy = fmaf(ay, dd, bb.y);
    float oz = fmaf(az, dd, bb.z);
    float ow = fmaf(aw, dd, bb.w);
    if (HOUT) {
        half4_t o;
        o.x = (_Float16)fmaxf(ox, 0.f);
        o.y = (_Float16)fmaxf(oy, 0.f);
        o.z = (_Float16)fmaxf(oz, 0.f);
        o.w = (_Float16)fmaxf(ow, 0.f);
        ((half4_t*)out)[(size_t)node * stride4 + lane] = o;
    } else {
        float4 o = make_float4(ox, oy, oz, ow);
        ((float4*)out)[(size_t)node * stride4 + lane] = o;
    }
}

// ---------------- MLP head (applies relu on input) ----------------
__global__ void k_mlp(const float* __restrict__ xin,
                      const float* __restrict__ lw0, const float* __restrict__ lb0,
                      const float* __restrict__ lw1, const float* __restrict__ lb1,
                      const float* __restrict__ lw2, const float* __restrict__ lb2,
                      float* __restrict__ s, int n) {
    int i = blockIdx.x * blockDim.x + threadIdx.x;
    if (i >= n) return;
    float v[32];
    const float4* xp = (const float4*)(xin + (size_t)i * 32);
#pragma unroll
    for (int q = 0; q < 8; ++q) {
        float4 t = xp[q];
        v[4 * q + 0] = fmaxf(t.x, 0.f);
        v[4 * q + 1] = fmaxf(t.y, 0.f);
        v[4 * q + 2] = fmaxf(t.z, 0.f);
        v[4 * q + 3] = fmaxf(t.w, 0.f);
    }
    float a[16];
#pragma unroll
    for (int j = 0; j < 16; ++j) {
        float acc = lb0[j];
#pragma unroll
        for (int k = 0; k < 32; ++k) acc = fmaf(v[k], lw0[k * 16 + j], acc);
        a[j] = fmaxf(acc, 0.f);
    }
    float b8[8];
#pragma unroll
    for (int j = 0; j < 8; ++j) {
        float acc = lb1[j];
#pragma unroll
        for (int k = 0; k < 16; ++k) acc = fmaf(a[k], lw1[k * 8 + j], acc);
        b8[j] = fmaxf(acc, 0.f);
    }
    float z = lb2[0];
#pragma unroll
    for (int k = 0; k < 8; ++k) z = fmaf(b8[k], lw2[k], z);
    s[i] = 1.0f / (1.0f + expf(-z));
}

__global__ void k_pred(const float* __restrict__ s, const int* __restrict__ pe,
                       float* __restrict__ out, int ep) {
    int i = blockIdx.x * blockDim.x + threadIdx.x;
    if (i < ep) out[i] = s[pe[2 * i]] * s[pe[2 * i + 1]];
}

extern "C" void kernel_launch(void* const* d_in, const int* in_sizes, int n_in,
                              void* d_out, int out_size, void* d_ws, size_t ws_size,
                              hipStream_t stream) {
    const float* x   = (const float*)d_in[0];
    const int*   ei  = (const int*)d_in[1];
    const int*   pe  = (const int*)d_in[2];
    const float* cw0 = (const float*)d_in[3];
    const float* cb0 = (const float*)d_in[4];
    const float* cw1 = (const float*)d_in[5];
    const float* cb1 = (const float*)d_in[6];
    const float* cw2 = (const float*)d_in[7];
    const float* cb2 = (const float*)d_in[8];
    const float* lw0 = (const float*)d_in[9];
    const float* lb0 = (const float*)d_in[10];
    const float* lw1 = (const float*)d_in[11];
    const float* lb1 = (const float*)d_in[12];
    const float* lw2 = (const float*)d_in[13];
    const float* lb2 = (const float*)d_in[14];

    const int* src = ei;        // edge_index[0]
    const int* dst = ei + NE;   // edge_index[1]

    // workspace layout (~46 MB; R1 layout of 55 MB fit, so this does too)
    char* w = (char*)d_ws;
    float*          dis  = (float*)w;           w += sizeof(float) * NN;
    _Float16*       Xh   = (_Float16*)w;        w += sizeof(_Float16) * (size_t)NP * 128;  // GEMM A input
    _Float16*       A    = (_Float16*)w;        w += sizeof(_Float16) * (size_t)NN * 128;  // messages
    _Float16*       Hact = (_Float16*)w;        w += sizeof(_Float16) * (size_t)NP * 128;  // relu'd activations
    float*          B    = (float*)w;           w += sizeof(float) * (size_t)NN * 32;      // conv2 out (fp32)
    float*          sv   = (float*)w;           w += sizeof(float) * NN;
    _Float16*       WT0  = (_Float16*)w;        w += sizeof(_Float16) * 128 * 128;
    _Float16*       WT1  = (_Float16*)w;        w += sizeof(_Float16) * 64 * 128;
    _Float16*       WT2  = (_Float16*)w;        w += sizeof(_Float16) * 32 * 64;
    int*            cnt  = (int*)w;             w += sizeof(int) * NN;
    int*            off  = (int*)w;             w += sizeof(int) * (NN + 1);
    int*            cur  = (int*)w;             w += sizeof(int) * NN;
    unsigned short* csr  = (unsigned short*)w;  w += sizeof(unsigned short) * NE;
    int*            bsum = (int*)w;             w += sizeof(int) * 256;

    const int T = 256;
    const int NB = cdiv(NN, 256);

    // --- CSR build + normalization ---
    hipMemsetAsync(cnt, 0, sizeof(int) * NN, stream);
    k_count<<<cdiv(NE, T), T, 0, stream>>>(dst, cnt, NE);
    k_scan_local<<<NB, 256, 0, stream>>>(cnt, off, bsum, NN);
    k_scan_bsum<<<1, 256, 0, stream>>>(bsum, NB);
    k_finalize_off<<<cdiv(NN, T), T, 0, stream>>>(off, bsum, cur, cnt, dis, NN, NE);
    k_fill<<<cdiv(NE, T), T, 0, stream>>>(src, dst, cur, csr, NE);

    // --- prep: x -> fp16, W -> WT fp16 ---
    k_x2h<<<cdiv((long long)NN * 32, T), T, 0, stream>>>(x, (half4_t*)Xh, (long long)NN * 32);
    k_wprep<128, 128><<<cdiv(128 * 128, T), T, 0, stream>>>(cw0, WT0);
    k_wprep<128, 64><<<cdiv(128 * 64, T), T, 0, stream>>>(cw1, WT1);
    k_wprep<64, 32><<<cdiv(64 * 32, T), T, 0, stream>>>(cw2, WT2);

    // --- conv0: 128 -> 128, MFMA; messages in 2 x 64-ch slices ---
    k_gemm_mfma<128, 128, 2><<<NP / 64, 256, 0, stream>>>(Xh, WT0, dis, A, NN);
    k_aggregate_h<64, true><<<cdiv(NN, 16), 256, 0, stream>>>((half4_t*)A,                   dis, cb0,      off, csr, (half4_t*)Hact,      32, NN);
    k_aggregate_h<64, true><<<cdiv(NN, 16), 256, 0, stream>>>((half4_t*)A + (size_t)NN * 16, dis, cb0 + 64, off, csr, (half4_t*)Hact + 16, 32, NN);

    // --- conv1: 128 -> 64, MFMA on relu'd fp16 activations ---
    k_gemm_mfma<128, 64, 2><<<NP / 128, 256, 0, stream>>>(Hact, WT1, dis, A, NN);
    k_aggregate_h<32, true><<<cdiv(NN, 32), 256, 0, stream>>>((half4_t*)A,                  dis, cb1,      off, csr, (half4_t*)Hact,     16, NN);
    k_aggregate_h<32, true><<<cdiv(NN, 32), 256, 0, stream>>>((half4_t*)A + (size_t)NN * 8, dis, cb1 + 32, off, csr, (half4_t*)Hact + 8, 16, NN);

    // --- conv2: 64 -> 32, MFMA; fp32 out for MLP ---
    k_gemm_mfma<64, 32, 1><<<NP / 128, 256, 0, stream>>>(Hact, WT2, dis, A, NN);
    k_aggregate_h<32, false><<<cdiv(NN, 32), 256, 0, stream>>>((half4_t*)A, dis, cb2, off, csr, B, 8, NN);

    // --- MLP head + link prediction ---
    k_mlp<<<cdiv(NN, T), T, 0, stream>>>(B, lw0, lb0, lw1, lb1, lw2, lb2, sv, NN);
    k_pred<<<cdiv(NEP, T), T, 0, stream>>>(sv, pe, (float*)d_out, NEP);
}

// Round 7
// 276.485 us; speedup vs baseline: 10.1348x; 1.1429x over previous
//
#include <hip/hip_runtime.h>
#include <math.h>

constexpr int NN  = 50000;   // nodes (< 65536 -> csr fits in ushort)
constexpr int NP  = 50048;   // padded rows (multiple of 128)
constexpr int NE  = 800000;  // edges
constexpr int NEP = 200000;  // pred edges

// CSR-build binning
constexpr int NBKT  = 256;   // bins; bin = dst >> 8 (256 nodes per bin, covers 65536)
constexpr int CAP   = 4096;  // per-bin capacity (mean 3125, ~17 sigma slack)
constexpr int CHUNK = 1024;  // edges per bucket workgroup

typedef _Float16 half4_t __attribute__((ext_vector_type(4)));
typedef _Float16 half8_t __attribute__((ext_vector_type(8)));
typedef float    float4_t __attribute__((ext_vector_type(4)));

static inline int cdiv(long long a, int b) { return (int)((a + b - 1) / b); }

// ---------------- CSR build: phase A — bucket edges by dst range ----------------
__global__ __launch_bounds__(256) void k_bucket(const int* __restrict__ src,
        const int* __restrict__ dst, int* __restrict__ binCnt,
        unsigned int* __restrict__ ebuf, int e) {
    __shared__ int hist[NBKT];
    __shared__ int base[NBKT];
    __shared__ int cur[NBKT];
    const int tid = threadIdx.x;
    const int e0  = blockIdx.x * CHUNK;
    hist[tid] = 0;
    __syncthreads();

    int  s[4], bn[4], dl[4];
    bool ok[4];
#pragma unroll
    for (int j = 0; j < 4; ++j) {
        int i = e0 + j * 256 + tid;
        ok[j] = i < e;
        if (ok[j]) {
            int d = dst[i];
            s[j]  = src[i];
            bn[j] = d >> 8;
            dl[j] = d & 255;
            atomicAdd(&hist[bn[j]], 1);
        }
    }
    __syncthreads();
    base[tid] = hist[tid] ? atomicAdd(&binCnt[tid], hist[tid]) : 0;
    cur[tid] = 0;
    __syncthreads();
#pragma unroll
    for (int j = 0; j < 4; ++j) {
        if (ok[j]) {
            int slot = base[bn[j]] + atomicAdd(&cur[bn[j]], 1);
            ebuf[bn[j] * CAP + slot] = (unsigned int)s[j] | ((unsigned int)dl[j] << 16);
        }
    }
}

// ---------------- phase A2: exclusive scan of bin counts ----------------
__global__ void k_binscan(const int* __restrict__ binCnt, int* __restrict__ binStart) {
    __shared__ int sh[NBKT];
    int tid = threadIdx.x;
    int v = binCnt[tid];
    sh[tid] = v;
    __syncthreads();
    for (int d = 1; d < NBKT; d <<= 1) {
        int t = (tid >= d) ? sh[tid - d] : 0;
        __syncthreads();
        sh[tid] += t;
        __syncthreads();
    }
    binStart[tid] = sh[tid] - v;   // exclusive
    if (tid == NBKT - 1) binStart[NBKT] = sh[tid];
}

// ---------------- phase B: per-bin CSR segment + off + dis ----------------
__global__ __launch_bounds__(256) void k_csrbuild(const unsigned int* __restrict__ ebuf,
        const int* __restrict__ binCnt, const int* __restrict__ binStart,
        int* __restrict__ off, float* __restrict__ dis,
        unsigned short* __restrict__ csr) {
    __shared__ int hist[256];
    __shared__ int sh[256];
    __shared__ int cur[256];
    const int tid   = threadIdx.x;
    const int bin   = blockIdx.x;
    const int cnt   = binCnt[bin];
    const int start = binStart[bin];
    const unsigned int* eb = ebuf + (size_t)bin * CAP;

    hist[tid] = 0;
    __syncthreads();
    for (int i = tid; i < cnt; i += 256)
        atomicAdd(&hist[eb[i] >> 16], 1);
    __syncthreads();

    int v = hist[tid];
    sh[tid] = v;
    __syncthreads();
    for (int d = 1; d < 256; d <<= 1) {
        int t = (tid >= d) ? sh[tid - d] : 0;
        __syncthreads();
        sh[tid] += t;
        __syncthreads();
    }
    int excl = sh[tid] - v;            // local exclusive prefix
    int gpos = start + excl;           // global csr offset for this node

    int node = bin * 256 + tid;
    if (node <= NN) off[node] = gpos;  // off[NN] lands here too (boundary = NE)
    if (node < NN)  dis[node] = rsqrtf((float)v + 1.0f);
    cur[tid] = gpos;
    __syncthreads();

    for (int i = tid; i < cnt; i += 256) {
        unsigned int e = eb[i];
        int p = atomicAdd(&cur[e >> 16], 1);
        csr[p] = (unsigned short)(e & 0xFFFFu);
    }
}

// ---------------- prep: x fp32 -> fp16 row-major ----------------
__global__ void k_x2h(const float* __restrict__ x, half4_t* __restrict__ X, long long n4) {
    long long i = (long long)blockIdx.x * blockDim.x + threadIdx.x;
    if (i >= n4) return;
    float4 v = ((const float4*)x)[i];
    half4_t o;
    o.x = (_Float16)v.x; o.y = (_Float16)v.y; o.z = (_Float16)v.z; o.w = (_Float16)v.w;
    X[i] = o;
}

// ---------------- prep: W (KxN fp32) -> WT (NxK fp16) ----------------
template<int K, int N>
__global__ void k_wprep(const float* __restrict__ W, _Float16* __restrict__ WT) {
    int idx = blockIdx.x * blockDim.x + threadIdx.x;
    if (idx >= K * N) return;
    int k = idx / N, n = idx - k * N;
    WT[(size_t)n * K + k] = (_Float16)W[idx];
}

// ---------------- MFMA GEMM: g = dis * (X @ WT^T), fp16 in/out ----------------
// X: NP x K fp16 row-major. WT: DOUT x K fp16 (pre-transposed W).
// Output: prescaled fp16 messages in SPLIT channel slices (n x DOUT/SPLIT each).
template<int K, int DOUT, int SPLIT>
__global__ __launch_bounds__(256) void k_gemm_mfma(const _Float16* __restrict__ X,
        const _Float16* __restrict__ WT, const float* __restrict__ dis,
        _Float16* __restrict__ g, int n) {
    constexpr int CW = (DOUT >= 128) ? 2 : 1;  // col wave-groups
    constexpr int RW = 4 / CW;                 // row wave-groups
    constexpr int NC = DOUT / CW;              // cols per wave
    constexpr int NT = NC / 16;                // 16-col tiles per wave
    constexpr int KT = K / 32;                 // K steps
    constexpr int MT = 2;                      // 16-row tiles per wave (32 rows)
    constexpr int BR = RW * 32;                // rows per block
    constexpr int SW = DOUT / SPLIT;           // slice width (fp16 elems)

    const int tid  = threadIdx.x;
    const int L    = tid & 63;
    const int w    = tid >> 6;
    const int wc   = w % CW;
    const int wr   = w / CW;
    const int r0   = blockIdx.x * BR + wr * 32;
    const int c0   = wc * NC;
    const int quad = L >> 4;
    const int lm   = L & 15;

    float4_t acc[MT][NT];
#pragma unroll
    for (int mt = 0; mt < MT; ++mt)
#pragma unroll
        for (int nt = 0; nt < NT; ++nt) acc[mt][nt] = (float4_t){0.f, 0.f, 0.f, 0.f};

#pragma unroll
    for (int kt = 0; kt < KT; ++kt) {
        half8_t a[MT], b[NT];
#pragma unroll
        for (int mt = 0; mt < MT; ++mt)
            a[mt] = *(const half8_t*)(X + (size_t)(r0 + mt * 16 + lm) * K + kt * 32 + quad * 8);
#pragma unroll
        for (int nt = 0; nt < NT; ++nt)
            b[nt] = *(const half8_t*)(WT + (size_t)(c0 + nt * 16 + lm) * K + kt * 32 + quad * 8);
#pragma unroll
        for (int mt = 0; mt < MT; ++mt)
#pragma unroll
            for (int nt = 0; nt < NT; ++nt)
                acc[mt][nt] = __builtin_amdgcn_mfma_f32_16x16x32_f16(a[mt], b[nt], acc[mt][nt], 0, 0, 0);
    }

    // epilogue: D[row=quad*4+reg][col=lm], scale by dis[row], store fp16 slices
#pragma unroll
    for (int mt = 0; mt < MT; ++mt) {
        int rb = r0 + mt * 16 + quad * 4;
        float dv[4];
        *(float4*)dv = *(const float4*)(dis + rb);
#pragma unroll
        for (int nt = 0; nt < NT; ++nt) {
            int c     = c0 + nt * 16 + lm;
            int slice = c / SW;
            int cl    = c - slice * SW;
            _Float16* gp = g + (size_t)slice * n * SW + cl;
#pragma unroll
            for (int reg = 0; reg < 4; ++reg) {
                int r = rb + reg;
                if (r < n) gp[(size_t)r * SW] = (_Float16)(acc[mt][nt][reg] * dv[reg]);
            }
        }
    }
}

// ---------------- CSR gather aggregation over one channel slice ----------------
// acc = g[d] + sum_{s in N(d)} g[s];  out = dis[d]*acc + b
// HOUT: write relu(out) as half4 (next layer's GEMM input); else float4 raw.
template<int DC, bool HOUT>
__global__ __launch_bounds__(256) void k_aggregate_h(const half4_t* __restrict__ g,
        const float* __restrict__ dis, const float* __restrict__ b,
        const int* __restrict__ off, const unsigned short* __restrict__ csr,
        void* __restrict__ out, int stride4, int n) {
    constexpr int TPN = DC / 4;     // half4 lanes per node
    constexpr int NPB = 256 / TPN;  // nodes per block
    int lane = threadIdx.x % TPN;
    int node = blockIdx.x * NPB + threadIdx.x / TPN;
    if (node >= n) return;
    float dd = dis[node];
    half4_t hv = g[(size_t)node * TPN + lane];
    float ax = (float)hv.x, ay = (float)hv.y, az = (float)hv.z, aw = (float)hv.w;
    int e0 = off[node], e1 = off[node + 1];
    int e = e0;
    for (; e + 3 < e1; e += 4) {
        int s0 = csr[e], s1 = csr[e + 1], s2 = csr[e + 2], s3 = csr[e + 3];
        half4_t v0 = g[(size_t)s0 * TPN + lane];
        half4_t v1 = g[(size_t)s1 * TPN + lane];
        half4_t v2 = g[(size_t)s2 * TPN + lane];
        half4_t v3 = g[(size_t)s3 * TPN + lane];
        ax += (float)v0.x; ay += (float)v0.y; az += (float)v0.z; aw += (float)v0.w;
        ax += (float)v1.x; ay += (float)v1.y; az += (float)v1.z; aw += (float)v1.w;
        ax += (float)v2.x; ay += (float)v2.y; az += (float)v2.z; aw += (float)v2.w;
        ax += (float)v3.x; ay += (float)v3.y; az += (float)v3.z; aw += (float)v3.w;
    }
    for (; e < e1; ++e) {
        int s0 = csr[e];
        half4_t v0 = g[(size_t)s0 * TPN + lane];
        ax += (float)v0.x; ay += (float)v0.y; az += (float)v0.z; aw += (float)v0.w;
    }
    float4 bb = ((const float4*)b)[lane];
    float ox = fmaf(ax, dd, bb.x);
    float oy = fmaf(ay, dd, bb.y);
    float oz = fmaf(az, dd, bb.z);
    float ow = fmaf(aw, dd, bb.w);
    if (HOUT) {
        half4_t o;
        o.x = (_Float16)fmaxf(ox, 0.f);
        o.y = (_Float16)fmaxf(oy, 0.f);
        o.z = (_Float16)fmaxf(oz, 0.f);
        o.w = (_Float16)fmaxf(ow, 0.f);
        ((half4_t*)out)[(size_t)node * stride4 + lane] = o;
    } else {
        float4 o = make_float4(ox, oy, oz, ow);
        ((float4*)out)[(size_t)node * stride4 + lane] = o;
    }
}

// ---------------- MLP head (applies relu on input) ----------------
__global__ void k_mlp(const float* __restrict__ xin,
                      const float* __restrict__ lw0, const float* __restrict__ lb0,
                      const float* __restrict__ lw1, const float* __restrict__ lb1,
                      const float* __restrict__ lw2, const float* __restrict__ lb2,
                      float* __restrict__ s, int n) {
    int i = blockIdx.x * blockDim.x + threadIdx.x;
    if (i >= n) return;
    float v[32];
    const float4* xp = (const float4*)(xin + (size_t)i * 32);
#pragma unroll
    for (int q = 0; q < 8; ++q) {
        float4 t = xp[q];
        v[4 * q + 0] = fmaxf(t.x, 0.f);
        v[4 * q + 1] = fmaxf(t.y, 0.f);
        v[4 * q + 2] = fmaxf(t.z, 0.f);
        v[4 * q + 3] = fmaxf(t.w, 0.f);
    }
    float a[16];
#pragma unroll
    for (int j = 0; j < 16; ++j) {
        float acc = lb0[j];
#pragma unroll
        for (int k = 0; k < 32; ++k) acc = fmaf(v[k], lw0[k * 16 + j], acc);
        a[j] = fmaxf(acc, 0.f);
    }
    float b8[8];
#pragma unroll
    for (int j = 0; j < 8; ++j) {
        float acc = lb1[j];
#pragma unroll
        for (int k = 0; k < 16; ++k) acc = fmaf(a[k], lw1[k * 8 + j], acc);
        b8[j] = fmaxf(acc, 0.f);
    }
    float z = lb2[0];
#pragma unroll
    for (int k = 0; k < 8; ++k) z = fmaf(b8[k], lw2[k], z);
    s[i] = 1.0f / (1.0f + expf(-z));
}

__global__ void k_pred(const float* __restrict__ s, const int* __restrict__ pe,
                       float* __restrict__ out, int ep) {
    int i = blockIdx.x * blockDim.x + threadIdx.x;
    if (i < ep) out[i] = s[pe[2 * i]] * s[pe[2 * i + 1]];
}

extern "C" void kernel_launch(void* const* d_in, const int* in_sizes, int n_in,
                              void* d_out, int out_size, void* d_ws, size_t ws_size,
                              hipStream_t stream) {
    const float* x   = (const float*)d_in[0];
    const int*   ei  = (const int*)d_in[1];
    const int*   pe  = (const int*)d_in[2];
    const float* cw0 = (const float*)d_in[3];
    const float* cb0 = (const float*)d_in[4];
    const float* cw1 = (const float*)d_in[5];
    const float* cb1 = (const float*)d_in[6];
    const float* cw2 = (const float*)d_in[7];
    const float* cb2 = (const float*)d_in[8];
    const float* lw0 = (const float*)d_in[9];
    const float* lb0 = (const float*)d_in[10];
    const float* lw1 = (const float*)d_in[11];
    const float* lb1 = (const float*)d_in[12];
    const float* lw2 = (const float*)d_in[13];
    const float* lb2 = (const float*)d_in[14];

    const int* src = ei;        // edge_index[0]
    const int* dst = ei + NE;   // edge_index[1]

    // workspace layout (~51 MB)
    char* w = (char*)d_ws;
    float*          dis  = (float*)w;           w += sizeof(float) * NN;
    _Float16*       Xh   = (_Float16*)w;        w += sizeof(_Float16) * (size_t)NP * 128;  // GEMM A input
    _Float16*       A    = (_Float16*)w;        w += sizeof(_Float16) * (size_t)NN * 128;  // messages
    _Float16*       Hact = (_Float16*)w;        w += sizeof(_Float16) * (size_t)NP * 128;  // relu'd activations
    float*          B    = (float*)w;           w += sizeof(float) * (size_t)NN * 32;      // conv2 out (fp32)
    float*          sv   = (float*)w;           w += sizeof(float) * NN;
    _Float16*       WT0  = (_Float16*)w;        w += sizeof(_Float16) * 128 * 128;
    _Float16*       WT1  = (_Float16*)w;        w += sizeof(_Float16) * 64 * 128;
    _Float16*       WT2  = (_Float16*)w;        w += sizeof(_Float16) * 32 * 64;
    int*            off  = (int*)w;             w += sizeof(int) * (NN + 1);
    unsigned short* csr  = (unsigned short*)w;  w += sizeof(unsigned short) * NE;
    int*            binCnt   = (int*)w;         w += sizeof(int) * NBKT;
    int*            binStart = (int*)w;         w += sizeof(int) * (NBKT + 1);
    unsigned int*   ebuf = (unsigned int*)w;    w += sizeof(unsigned int) * (size_t)NBKT * CAP;

    const int T = 256;

    // --- CSR build (binned radix scatter) + normalization ---
    hipMemsetAsync(binCnt, 0, sizeof(int) * NBKT, stream);
    k_bucket<<<cdiv(NE, CHUNK), 256, 0, stream>>>(src, dst, binCnt, ebuf, NE);
    k_binscan<<<1, NBKT, 0, stream>>>(binCnt, binStart);
    k_csrbuild<<<NBKT, 256, 0, stream>>>(ebuf, binCnt, binStart, off, dis, csr);

    // --- prep: x -> fp16, W -> WT fp16 ---
    k_x2h<<<cdiv((long long)NN * 32, T), T, 0, stream>>>(x, (half4_t*)Xh, (long long)NN * 32);
    k_wprep<128, 128><<<cdiv(128 * 128, T), T, 0, stream>>>(cw0, WT0);
    k_wprep<128, 64><<<cdiv(128 * 64, T), T, 0, stream>>>(cw1, WT1);
    k_wprep<64, 32><<<cdiv(64 * 32, T), T, 0, stream>>>(cw2, WT2);

    // --- conv0: 128 -> 128, MFMA; messages in 2 x 64-ch slices ---
    k_gemm_mfma<128, 128, 2><<<NP / 64, 256, 0, stream>>>(Xh, WT0, dis, A, NN);
    k_aggregate_h<64, true><<<cdiv(NN, 16), 256, 0, stream>>>((half4_t*)A,                   dis, cb0,      off, csr, (half4_t*)Hact,      32, NN);
    k_aggregate_h<64, true><<<cdiv(NN, 16), 256, 0, stream>>>((half4_t*)A + (size_t)NN * 16, dis, cb0 + 64, off, csr, (half4_t*)Hact + 16, 32, NN);

    // --- conv1: 128 -> 64, MFMA on relu'd fp16 activations ---
    k_gemm_mfma<128, 64, 2><<<NP / 128, 256, 0, stream>>>(Hact, WT1, dis, A, NN);
    k_aggregate_h<32, true><<<cdiv(NN, 32), 256, 0, stream>>>((half4_t*)A,                  dis, cb1,      off, csr, (half4_t*)Hact,     16, NN);
    k_aggregate_h<32, true><<<cdiv(NN, 32), 256, 0, stream>>>((half4_t*)A + (size_t)NN * 8, dis, cb1 + 32, off, csr, (half4_t*)Hact + 8, 16, NN);

    // --- conv2: 64 -> 32, MFMA; fp32 out for MLP ---
    k_gemm_mfma<64, 32, 1><<<NP / 128, 256, 0, stream>>>(Hact, WT2, dis, A, NN);
    k_aggregate_h<32, false><<<cdiv(NN, 32), 256, 0, stream>>>((half4_t*)A, dis, cb2, off, csr, B, 8, NN);

    // --- MLP head + link prediction ---
    k_mlp<<<cdiv(NN, T), T, 0, stream>>>(B, lw0, lb0, lw1, lb1, lw2, lb2, sv, NN);
    k_pred<<<cdiv(NEP, T), T, 0, stream>>>(sv, pe, (float*)d_out, NEP);
}

// Round 8
// 253.864 us; speedup vs baseline: 11.0379x; 1.0891x over previous
//
#include <hip/hip_runtime.h>
#include <math.h>

constexpr int NN  = 50000;   // nodes (< 65536 -> csr fits in ushort)
constexpr int NP  = 50048;   // padded rows (multiple of 128)
constexpr int NE  = 800000;  // edges
constexpr int NEP = 200000;  // pred edges

// CSR-build binning
constexpr int NBKT  = 256;   // bins; bin = dst >> 8
constexpr int CAP   = 4096;  // per-bin capacity (mean 3125, ~17 sigma slack)
constexpr int CHUNK = 1024;  // edges per bucket workgroup

// fused front-end block ranges
constexpr int BKB = (NE + CHUNK - 1) / CHUNK;          // 782 bucket blocks
constexpr int XB  = (NN * 32 + 255) / 256;             // 6250 x2h blocks
constexpr int W0B = 128 * 128 / 256;                   // 64
constexpr int W1B = 128 * 64 / 256;                    // 32
constexpr int W2B = 64 * 32 / 256;                     // 8
constexpr int FRONT_BLOCKS = BKB + XB + W0B + W1B + W2B;

typedef _Float16 half4_t __attribute__((ext_vector_type(4)));
typedef _Float16 half8_t __attribute__((ext_vector_type(8)));
typedef float    float4_t __attribute__((ext_vector_type(4)));

static inline int cdiv(long long a, int b) { return (int)((a + b - 1) / b); }

// ---------------- fused front end: bucket edges + x->fp16 + W transposes ----------------
__global__ __launch_bounds__(256) void k_front(const int* __restrict__ src,
        const int* __restrict__ dst, int* __restrict__ binCnt,
        unsigned int* __restrict__ ebuf,
        const float* __restrict__ x, half4_t* __restrict__ Xh,
        const float* __restrict__ cw0, _Float16* __restrict__ WT0,
        const float* __restrict__ cw1, _Float16* __restrict__ WT1,
        const float* __restrict__ cw2, _Float16* __restrict__ WT2) {
    const int tid = threadIdx.x;
    const int bid = blockIdx.x;

    if (bid < BKB) {
        // ---- bucket edges by dst>>8 ----
        __shared__ int hist[NBKT];
        __shared__ int base[NBKT];
        __shared__ int cur[NBKT];
        const int e0 = bid * CHUNK;
        hist[tid] = 0;
        __syncthreads();
        int  s[4], bn[4], dl[4];
        bool ok[4];
#pragma unroll
        for (int j = 0; j < 4; ++j) {
            int i = e0 + j * 256 + tid;
            ok[j] = i < NE;
            if (ok[j]) {
                int d = dst[i];
                s[j]  = src[i];
                bn[j] = d >> 8;
                dl[j] = d & 255;
                atomicAdd(&hist[bn[j]], 1);
            }
        }
        __syncthreads();
        base[tid] = hist[tid] ? atomicAdd(&binCnt[tid], hist[tid]) : 0;
        cur[tid] = 0;
        __syncthreads();
#pragma unroll
        for (int j = 0; j < 4; ++j) {
            if (ok[j]) {
                int slot = base[bn[j]] + atomicAdd(&cur[bn[j]], 1);
                ebuf[bn[j] * CAP + slot] = (unsigned int)s[j] | ((unsigned int)dl[j] << 16);
            }
        }
        return;
    }
    if (bid < BKB + XB) {
        // ---- x fp32 -> fp16 ----
        long long i = (long long)(bid - BKB) * 256 + tid;
        if (i < (long long)NN * 32) {
            float4 v = ((const float4*)x)[i];
            half4_t o;
            o.x = (_Float16)v.x; o.y = (_Float16)v.y; o.z = (_Float16)v.z; o.w = (_Float16)v.w;
            Xh[i] = o;
        }
        return;
    }
    if (bid < BKB + XB + W0B) {
        int idx = (bid - BKB - XB) * 256 + tid;
        int k = idx >> 7, n = idx & 127;            // K=128, N=128
        WT0[(size_t)n * 128 + k] = (_Float16)cw0[idx];
        return;
    }
    if (bid < BKB + XB + W0B + W1B) {
        int idx = (bid - BKB - XB - W0B) * 256 + tid;
        int k = idx >> 6, n = idx & 63;             // K=128, N=64
        WT1[(size_t)n * 128 + k] = (_Float16)cw1[idx];
        return;
    }
    {
        int idx = (bid - BKB - XB - W0B - W1B) * 256 + tid;
        int k = idx >> 5, n = idx & 31;             // K=64, N=32
        WT2[(size_t)n * 64 + k] = (_Float16)cw2[idx];
    }
}

// ---------------- CSR build: per-bin segment + off + dis (self-scans binCnt) ----------------
__global__ __launch_bounds__(256) void k_csrbuild(const unsigned int* __restrict__ ebuf,
        const int* __restrict__ binCnt, int* __restrict__ off, float* __restrict__ dis,
        unsigned short* __restrict__ csr) {
    __shared__ int borig[NBKT];
    __shared__ int bscan[NBKT];
    __shared__ int hist[256];
    __shared__ int sh[256];
    __shared__ int cur[256];
    const int tid = threadIdx.x;
    const int bin = blockIdx.x;

    // scan bin counts (all blocks redundantly; cheap)
    int bv = binCnt[tid];
    borig[tid] = bv;
    bscan[tid] = bv;
    __syncthreads();
    for (int d = 1; d < NBKT; d <<= 1) {
        int t = (tid >= d) ? bscan[tid - d] : 0;
        __syncthreads();
        bscan[tid] += t;
        __syncthreads();
    }
    const int cnt   = borig[bin];
    const int start = bscan[bin] - cnt;   // exclusive prefix
    const unsigned int* eb = ebuf + (size_t)bin * CAP;

    hist[tid] = 0;
    __syncthreads();
    for (int i = tid; i < cnt; i += 256)
        atomicAdd(&hist[eb[i] >> 16], 1);
    __syncthreads();

    int v = hist[tid];
    sh[tid] = v;
    __syncthreads();
    for (int d = 1; d < 256; d <<= 1) {
        int t = (tid >= d) ? sh[tid - d] : 0;
        __syncthreads();
        sh[tid] += t;
        __syncthreads();
    }
    int gpos = start + sh[tid] - v;       // global csr offset for this node

    int node = bin * 256 + tid;
    if (node <= NN) off[node] = gpos;     // off[NN] = NE lands here (later bins empty)
    if (node < NN)  dis[node] = rsqrtf((float)v + 1.0f);
    cur[tid] = gpos;
    __syncthreads();

    for (int i = tid; i < cnt; i += 256) {
        unsigned int e = eb[i];
        int p = atomicAdd(&cur[e >> 16], 1);
        csr[p] = (unsigned short)(e & 0xFFFFu);
    }
}

// ---------------- MFMA GEMM: g = dis * (X @ WT^T), fp16 in/out ----------------
template<int K, int DOUT, int SPLIT>
__global__ __launch_bounds__(256) void k_gemm_mfma(const _Float16* __restrict__ X,
        const _Float16* __restrict__ WT, const float* __restrict__ dis,
        _Float16* __restrict__ g, int n) {
    constexpr int CW = (DOUT >= 128) ? 2 : 1;
    constexpr int RW = 4 / CW;
    constexpr int NC = DOUT / CW;
    constexpr int NT = NC / 16;
    constexpr int KT = K / 32;
    constexpr int MT = 2;
    constexpr int BR = RW * 32;
    constexpr int SW = DOUT / SPLIT;

    const int tid  = threadIdx.x;
    const int L    = tid & 63;
    const int w    = tid >> 6;
    const int wc   = w % CW;
    const int wr   = w / CW;
    const int r0   = blockIdx.x * BR + wr * 32;
    const int c0   = wc * NC;
    const int quad = L >> 4;
    const int lm   = L & 15;

    float4_t acc[MT][NT];
#pragma unroll
    for (int mt = 0; mt < MT; ++mt)
#pragma unroll
        for (int nt = 0; nt < NT; ++nt) acc[mt][nt] = (float4_t){0.f, 0.f, 0.f, 0.f};

#pragma unroll
    for (int kt = 0; kt < KT; ++kt) {
        half8_t a[MT], b[NT];
#pragma unroll
        for (int mt = 0; mt < MT; ++mt)
            a[mt] = *(const half8_t*)(X + (size_t)(r0 + mt * 16 + lm) * K + kt * 32 + quad * 8);
#pragma unroll
        for (int nt = 0; nt < NT; ++nt)
            b[nt] = *(const half8_t*)(WT + (size_t)(c0 + nt * 16 + lm) * K + kt * 32 + quad * 8);
#pragma unroll
        for (int mt = 0; mt < MT; ++mt)
#pragma unroll
            for (int nt = 0; nt < NT; ++nt)
                acc[mt][nt] = __builtin_amdgcn_mfma_f32_16x16x32_f16(a[mt], b[nt], acc[mt][nt], 0, 0, 0);
    }

#pragma unroll
    for (int mt = 0; mt < MT; ++mt) {
        int rb = r0 + mt * 16 + quad * 4;
        float dv[4];
        *(float4*)dv = *(const float4*)(dis + rb);
#pragma unroll
        for (int nt = 0; nt < NT; ++nt) {
            int c     = c0 + nt * 16 + lm;
            int slice = c / SW;
            int cl    = c - slice * SW;
            _Float16* gp = g + (size_t)slice * n * SW + cl;
#pragma unroll
            for (int reg = 0; reg < 4; ++reg) {
                int r = rb + reg;
                if (r < n) gp[(size_t)r * SW] = (_Float16)(acc[mt][nt][reg] * dv[reg]);
            }
        }
    }
}

// ---------------- CSR gather aggregation; blockIdx.y = channel slice ----------------
// acc = g[d] + sum g[s];  out = relu(dis[d]*acc + b) as fp16 (next GEMM input)
template<int DC>
__global__ __launch_bounds__(256) void k_aggregate_h(const half4_t* __restrict__ gBase,
        const float* __restrict__ dis, const float* __restrict__ bBase,
        const int* __restrict__ off, const unsigned short* __restrict__ csr,
        half4_t* __restrict__ outBase, int stride4, int n) {
    constexpr int TPN = DC / 4;
    constexpr int NPB = 256 / TPN;
    const int slice = blockIdx.y;
    const half4_t* g = gBase + (size_t)slice * n * TPN;
    const float4* bb4 = (const float4*)bBase + slice * TPN;
    half4_t* out = outBase + slice * TPN;

    int lane = threadIdx.x % TPN;
    int node = blockIdx.x * NPB + threadIdx.x / TPN;
    if (node >= n) return;
    float dd = dis[node];
    half4_t hv = g[(size_t)node * TPN + lane];
    float ax = (float)hv.x, ay = (float)hv.y, az = (float)hv.z, aw = (float)hv.w;
    int e0 = off[node], e1 = off[node + 1];
    int e = e0;
    for (; e + 3 < e1; e += 4) {
        int s0 = csr[e], s1 = csr[e + 1], s2 = csr[e + 2], s3 = csr[e + 3];
        half4_t v0 = g[(size_t)s0 * TPN + lane];
        half4_t v1 = g[(size_t)s1 * TPN + lane];
        half4_t v2 = g[(size_t)s2 * TPN + lane];
        half4_t v3 = g[(size_t)s3 * TPN + lane];
        ax += (float)v0.x; ay += (float)v0.y; az += (float)v0.z; aw += (float)v0.w;
        ax += (float)v1.x; ay += (float)v1.y; az += (float)v1.z; aw += (float)v1.w;
        ax += (float)v2.x; ay += (float)v2.y; az += (float)v2.z; aw += (float)v2.w;
        ax += (float)v3.x; ay += (float)v3.y; az += (float)v3.z; aw += (float)v3.w;
    }
    for (; e < e1; ++e) {
        int s0 = csr[e];
        half4_t v0 = g[(size_t)s0 * TPN + lane];
        ax += (float)v0.x; ay += (float)v0.y; az += (float)v0.z; aw += (float)v0.w;
    }
    float4 bb = bb4[lane];
    half4_t o;
    o.x = (_Float16)fmaxf(fmaf(ax, dd, bb.x), 0.f);
    o.y = (_Float16)fmaxf(fmaf(ay, dd, bb.y), 0.f);
    o.z = (_Float16)fmaxf(fmaf(az, dd, bb.z), 0.f);
    o.w = (_Float16)fmaxf(fmaf(aw, dd, bb.w), 0.f);
    out[(size_t)node * stride4 + lane] = o;
}

// ---------------- conv2 aggregate (32ch) fused with MLP head -> node scores ----------------
__global__ __launch_bounds__(256) void k_agg_mlp(const half4_t* __restrict__ g,
        const float* __restrict__ dis, const float* __restrict__ b,
        const int* __restrict__ off, const unsigned short* __restrict__ csr,
        const float* __restrict__ lw0, const float* __restrict__ lb0,
        const float* __restrict__ lw1, const float* __restrict__ lb1,
        const float* __restrict__ lw2, const float* __restrict__ lb2,
        float* __restrict__ sv, int n) {
    constexpr int TPN = 8;    // half4 lanes per node (32 ch)
    constexpr int NPB = 32;   // nodes per block
    __shared__ float sh[NPB * 33];

    const int tid  = threadIdx.x;
    const int lane = tid % TPN;
    const int ln   = tid / TPN;            // local node
    const int node = blockIdx.x * NPB + ln;

    if (node < n) {
        float dd = dis[node];
        half4_t hv = g[(size_t)node * TPN + lane];
        float ax = (float)hv.x, ay = (float)hv.y, az = (float)hv.z, aw = (float)hv.w;
        int e0 = off[node], e1 = off[node + 1];
        int e = e0;
        for (; e + 3 < e1; e += 4) {
            int s0 = csr[e], s1 = csr[e + 1], s2 = csr[e + 2], s3 = csr[e + 3];
            half4_t v0 = g[(size_t)s0 * TPN + lane];
            half4_t v1 = g[(size_t)s1 * TPN + lane];
            half4_t v2 = g[(size_t)s2 * TPN + lane];
            half4_t v3 = g[(size_t)s3 * TPN + lane];
            ax += (float)v0.x; ay += (float)v0.y; az += (float)v0.z; aw += (float)v0.w;
            ax += (float)v1.x; ay += (float)v1.y; az += (float)v1.z; aw += (float)v1.w;
            ax += (float)v2.x; ay += (float)v2.y; az += (float)v2.z; aw += (float)v2.w;
            ax += (float)v3.x; ay += (float)v3.y; az += (float)v3.z; aw += (float)v3.w;
        }
        for (; e < e1; ++e) {
            int s0 = csr[e];
            half4_t v0 = g[(size_t)s0 * TPN + lane];
            ax += (float)v0.x; ay += (float)v0.y; az += (float)v0.z; aw += (float)v0.w;
        }
        const float4* bb4 = (const float4*)b;
        float4 bb = bb4[lane];
        float* row = sh + ln * 33 + lane * 4;
        row[0] = fmaxf(fmaf(ax, dd, bb.x), 0.f);   // relu applied here
        row[1] = fmaxf(fmaf(ay, dd, bb.y), 0.f);
        row[2] = fmaxf(fmaf(az, dd, bb.z), 0.f);
        row[3] = fmaxf(fmaf(aw, dd, bb.w), 0.f);
    }
    __syncthreads();

    if (tid < NPB) {
        int node2 = blockIdx.x * NPB + tid;
        if (node2 < n) {
            const float* v = sh + tid * 33;
            float a[16];
#pragma unroll
            for (int j = 0; j < 16; ++j) {
                float acc = lb0[j];
#pragma unroll
                for (int k = 0; k < 32; ++k) acc = fmaf(v[k], lw0[k * 16 + j], acc);
                a[j] = fmaxf(acc, 0.f);
            }
            float b8[8];
#pragma unroll
            for (int j = 0; j < 8; ++j) {
                float acc = lb1[j];
#pragma unroll
                for (int k = 0; k < 16; ++k) acc = fmaf(a[k], lw1[k * 8 + j], acc);
                b8[j] = fmaxf(acc, 0.f);
            }
            float z = lb2[0];
#pragma unroll
            for (int k = 0; k < 8; ++k) z = fmaf(b8[k], lw2[k], z);
            sv[node2] = 1.0f / (1.0f + expf(-z));
        }
    }
}

__global__ void k_pred(const float* __restrict__ s, const int* __restrict__ pe,
                       float* __restrict__ out, int ep) {
    int i = blockIdx.x * blockDim.x + threadIdx.x;
    if (i < ep) out[i] = s[pe[2 * i]] * s[pe[2 * i + 1]];
}

extern "C" void kernel_launch(void* const* d_in, const int* in_sizes, int n_in,
                              void* d_out, int out_size, void* d_ws, size_t ws_size,
                              hipStream_t stream) {
    const float* x   = (const float*)d_in[0];
    const int*   ei  = (const int*)d_in[1];
    const int*   pe  = (const int*)d_in[2];
    const float* cw0 = (const float*)d_in[3];
    const float* cb0 = (const float*)d_in[4];
    const float* cw1 = (const float*)d_in[5];
    const float* cb1 = (const float*)d_in[6];
    const float* cw2 = (const float*)d_in[7];
    const float* cb2 = (const float*)d_in[8];
    const float* lw0 = (const float*)d_in[9];
    const float* lb0 = (const float*)d_in[10];
    const float* lw1 = (const float*)d_in[11];
    const float* lb1 = (const float*)d_in[12];
    const float* lw2 = (const float*)d_in[13];
    const float* lb2 = (const float*)d_in[14];

    const int* src = ei;        // edge_index[0]
    const int* dst = ei + NE;   // edge_index[1]

    // workspace layout
    char* w = (char*)d_ws;
    float*          dis  = (float*)w;           w += sizeof(float) * NN;
    _Float16*       Xh   = (_Float16*)w;        w += sizeof(_Float16) * (size_t)NP * 128;
    _Float16*       A    = (_Float16*)w;        w += sizeof(_Float16) * (size_t)NN * 128;
    _Float16*       Hact = (_Float16*)w;        w += sizeof(_Float16) * (size_t)NP * 128;
    float*          sv   = (float*)w;           w += sizeof(float) * NN;
    _Float16*       WT0  = (_Float16*)w;        w += sizeof(_Float16) * 128 * 128;
    _Float16*       WT1  = (_Float16*)w;        w += sizeof(_Float16) * 64 * 128;
    _Float16*       WT2  = (_Float16*)w;        w += sizeof(_Float16) * 32 * 64;
    int*            off  = (int*)w;             w += sizeof(int) * (NN + 1);
    unsigned short* csr  = (unsigned short*)w;  w += sizeof(unsigned short) * NE;
    int*            binCnt = (int*)w;           w += sizeof(int) * NBKT;
    unsigned int*   ebuf = (unsigned int*)w;    w += sizeof(unsigned int) * (size_t)NBKT * CAP;

    const int T = 256;

    // --- front end: bucket + fp16 conversions (one launch) ---
    hipMemsetAsync(binCnt, 0, sizeof(int) * NBKT, stream);
    k_front<<<FRONT_BLOCKS, 256, 0, stream>>>(src, dst, binCnt, ebuf,
                                              x, (half4_t*)Xh, cw0, WT0, cw1, WT1, cw2, WT2);

    // --- CSR build (self-scanning) ---
    k_csrbuild<<<NBKT, 256, 0, stream>>>(ebuf, binCnt, off, dis, csr);

    // --- conv0: 128 -> 128 ---
    k_gemm_mfma<128, 128, 2><<<NP / 64, 256, 0, stream>>>(Xh, WT0, dis, A, NN);
    {
        dim3 gr(cdiv(NN, 16), 2);
        k_aggregate_h<64><<<gr, 256, 0, stream>>>((half4_t*)A, dis, cb0, off, csr,
                                                  (half4_t*)Hact, 32, NN);
    }

    // --- conv1: 128 -> 64 ---
    k_gemm_mfma<128, 64, 2><<<NP / 128, 256, 0, stream>>>(Hact, WT1, dis, A, NN);
    {
        dim3 gr(cdiv(NN, 32), 2);
        k_aggregate_h<32><<<gr, 256, 0, stream>>>((half4_t*)A, dis, cb1, off, csr,
                                                  (half4_t*)Hact, 16, NN);
    }

    // --- conv2: 64 -> 32, aggregate fused with MLP ---
    k_gemm_mfma<64, 32, 1><<<NP / 128, 256, 0, stream>>>(Hact, WT2, dis, A, NN);
    k_agg_mlp<<<cdiv(NN, 32), 256, 0, stream>>>((half4_t*)A, dis, cb2, off, csr,
                                                lw0, lb0, lw1, lb1, lw2, lb2, sv, NN);

    // --- link prediction ---
    k_pred<<<cdiv(NEP, T), T, 0, stream>>>(sv, pe, (float*)d_out, NEP);
}